// Round 7
// baseline (1800.846 us; speedup 1.0000x reference)
//
#include <hip/hip_runtime.h>
#include <math.h>
#include <stdint.h>

// Problem constants (from reference setup_inputs)
constexpr int SEQ   = 2048;  // T
constexpr int BATCH = 64;    // B
constexpr int EMB   = 100;   // E
constexpr int HID   = 128;   // H
constexpr int G3    = 384;   // 3*H
constexpr int NS    = 6;     // S (CRF states)
constexpr int BSEL  = 63;    // only batch row 63 affects the output

typedef _Float16 f16x8 __attribute__((ext_vector_type(8)));
typedef _Float16 f16x2 __attribute__((ext_vector_type(2)));
typedef float    f32x4 __attribute__((ext_vector_type(4)));

union U16x8 { uint4 u; f16x8 h; };

__device__ __forceinline__ uint32_t pack_f16(float a, float b) {
    f16x2 p; p.x = (_Float16)a; p.y = (_Float16)b;
    return __builtin_bit_cast(uint32_t, p);
}

// DPP mov from lane (me+s)&15 within each 16-lane row (row_ror:s = 0x120+s)
template <int CTRL>
__device__ __forceinline__ float dpp_movf(float x) {
    return __int_as_float(
        __builtin_amdgcn_update_dpp(0, __float_as_int(x), CTRL, 0xF, 0xF, true));
}

// ---------------------------------------------------------------------------
// Kernel 1: embedding lookup + input projection for batch row 63 only.
// (unchanged)
// ---------------------------------------------------------------------------
__global__ __launch_bounds__(G3) void k_input_proj(
    const int* __restrict__ sent, const float* __restrict__ emb,
    const float* __restrict__ Wf_ih, const float* __restrict__ bf_ih,
    const float* __restrict__ Wb_ih, const float* __restrict__ bb_ih,
    float* __restrict__ gi_f, float* __restrict__ gi_b)
{
    const int tb = blockIdx.x * 4;
    const int j  = threadIdx.x;           // 0..383
    __shared__ __align__(16) float x_s[4][EMB];

    int toks[4];
#pragma unroll
    for (int tt = 0; tt < 4; ++tt) toks[tt] = sent[BSEL * SEQ + tb + tt];
    if (j < EMB) {
#pragma unroll
        for (int tt = 0; tt < 4; ++tt)
            x_s[tt][j] = emb[(size_t)toks[tt] * EMB + j];
    }
    __syncthreads();

    float4 wf4[25], wb4[25];
    const float4* wfp = (const float4*)(Wf_ih + (size_t)j * EMB);
    const float4* wbp = (const float4*)(Wb_ih + (size_t)j * EMB);
#pragma unroll
    for (int m = 0; m < 25; ++m) { wf4[m] = wfp[m]; wb4[m] = wbp[m]; }
    const float bf = bf_ih[j], bb = bb_ih[j];

#pragma unroll
    for (int tt = 0; tt < 4; ++tt) {
        const float4* xs = (const float4*)(x_s[tt]);
        float af = 0.f, ab = 0.f;
#pragma unroll
        for (int m = 0; m < 25; ++m) {
            const float4 xv = xs[m];
            af = fmaf(wf4[m].x, xv.x, af); af = fmaf(wf4[m].y, xv.y, af);
            af = fmaf(wf4[m].z, xv.z, af); af = fmaf(wf4[m].w, xv.w, af);
            ab = fmaf(wb4[m].x, xv.x, ab); ab = fmaf(wb4[m].y, xv.y, ab);
            ab = fmaf(wb4[m].z, xv.z, ab); ab = fmaf(wb4[m].w, xv.w, ab);
        }
        gi_f[(tb + tt) * G3 + j] = af + bf;
        gi_b[(tb + tt) * G3 + j] = ab + bb;
    }
}

// ---------------------------------------------------------------------------
// Kernel 2: GRU recurrence on the MATRIX pipe. One block (512 thr) per dir.
// Wave w owns units [16w,16w+16). Per step, 12 x mfma_f32_16x16x32_f16
// (3 gates x 4 K-tiles): A = Whh fragments (lane gives A[m=lane&15]
// [k=32kt+8q+j], q=lane>>4) held resident (AGPR-friendly — MFMA reads
// AGPRs natively, no shuttle); B = h broadcast to all 16 cols (lane reads
// h[32kt+8q..+8] from LDS, 16-lane broadcast, 4 ds_read_b128/wave).
// D: col=lane&15 (all equal), row=4q+r -> lane computes gates for units
// 16w+4q+{0..3}; lanes n==0 write h (f16 pairs) + fp32 output.
// One barrier per step (double-buffered h).
// ---------------------------------------------------------------------------
__global__ __launch_bounds__(512, 1) void k_recur(
    const float* __restrict__ gi_f, const float* __restrict__ gi_b,
    const float* __restrict__ Wf_hh, const float* __restrict__ bf_hh,
    const float* __restrict__ Wb_hh, const float* __restrict__ bb_hh,
    const float* __restrict__ h0,
    float* __restrict__ fwd, float* __restrict__ bwd)
{
    const int dir = blockIdx.x;           // 0 = forward, 1 = backward
    const float* gi  = dir ? gi_b  : gi_f;
    const float* Whh = dir ? Wb_hh : Wf_hh;
    const float* bhh = dir ? bb_hh : bf_hh;
    float* outs      = dir ? bwd   : fwd;

    const int tid  = threadIdx.x;
    const int lane = tid & 63;
    const int wv   = tid >> 6;            // wave 0..7 -> units [16wv,16wv+16)
    const int q    = lane >> 4;           // 0..3
    const int n    = lane & 15;           // 0..15

    // A fragments: 3 gates x 4 K-tiles, f16. Lane supplies row m=n of the
    // 16-row tile, k-slice 32*kt + 8q .. +8.
    f16x8 Af[3][4];
#pragma unroll
    for (int g = 0; g < 3; ++g) {
        const float* wrow = Whh + (size_t)(g * HID + 16 * wv + n) * HID;
#pragma unroll
        for (int kt = 0; kt < 4; ++kt) {
            const float* p8 = wrow + 32 * kt + 8 * q;
            f16x8 a;
#pragma unroll
            for (int jj = 0; jj < 8; ++jj) a[jj] = (_Float16)p8[jj];
            Af[g][kt] = a;
        }
    }

    const int u4 = 16 * wv + 4 * q;       // this lane's 4 gate units
    const f32x4 b_r4 = *(const f32x4*)(bhh + u4);
    const f32x4 b_z4 = *(const f32x4*)(bhh + HID + u4);
    const f32x4 b_n4 = *(const f32x4*)(bhh + 2 * HID + u4);

    const int ginc = dir ? -G3 : G3;
    const int oinc = dir ? -HID : HID;
    const int t0   = dir ? (SEQ - 1) : 0;
    const float* gp = gi + (size_t)t0 * G3 + u4;
    float* op       = outs + (size_t)t0 * HID + u4;

    f32x4 hq = *(const f32x4*)(h0 + (size_t)dir * BATCH * HID + BSEL * HID + u4);

    f32x4 gcr, gcz, gcn;                  // current-step gi (+biases for r,z)
    {
        gcr = *(const f32x4*)gp + b_r4;
        gcz = *(const f32x4*)(gp + 128) + b_z4;
        gcn = *(const f32x4*)(gp + 256);
    }

    // h as packed f16 pairs: h_lds[buf][p] = {h[2p], h[2p+1]}
    __shared__ __align__(16) uint32_t h_lds[2][HID / 2];
    if (tid < HID / 2) {
        const float2 hh = *(const float2*)(h0 + (size_t)dir * BATCH * HID + BSEL * HID + 2 * tid);
        h_lds[0][tid] = pack_f16(hh.x, hh.y);
    }
    __syncthreads();

    const f32x4 z4 = {0.f, 0.f, 0.f, 0.f};

    auto body = [&](int cur) {
        // prefetch next step's gi (final-step overrun lands in the adjacent
        // gi buffer — valid memory, value discarded)
        const float* gpn = gp + ginc;
        const f32x4 pr = *(const f32x4*)gpn;
        const f32x4 pz = *(const f32x4*)(gpn + 128);
        const f32x4 pn = *(const f32x4*)(gpn + 256);

        // B fragments: lane reads h[32kt+8q .. +8] (16B, 16-lane broadcast)
        const uint4* hb = (const uint4*)(h_lds[cur]);
        U16x8 B0, B1, B2, B3;
        B0.u = hb[q];      B1.u = hb[q + 4];
        B2.u = hb[q + 8];  B3.u = hb[q + 12];

        f32x4 aR = __builtin_amdgcn_mfma_f32_16x16x32_f16(Af[0][0], B0.h, z4, 0, 0, 0);
        f32x4 aZ = __builtin_amdgcn_mfma_f32_16x16x32_f16(Af[1][0], B0.h, z4, 0, 0, 0);
        f32x4 aN = __builtin_amdgcn_mfma_f32_16x16x32_f16(Af[2][0], B0.h, z4, 0, 0, 0);
        aR = __builtin_amdgcn_mfma_f32_16x16x32_f16(Af[0][1], B1.h, aR, 0, 0, 0);
        aZ = __builtin_amdgcn_mfma_f32_16x16x32_f16(Af[1][1], B1.h, aZ, 0, 0, 0);
        aN = __builtin_amdgcn_mfma_f32_16x16x32_f16(Af[2][1], B1.h, aN, 0, 0, 0);
        aR = __builtin_amdgcn_mfma_f32_16x16x32_f16(Af[0][2], B2.h, aR, 0, 0, 0);
        aZ = __builtin_amdgcn_mfma_f32_16x16x32_f16(Af[1][2], B2.h, aZ, 0, 0, 0);
        aN = __builtin_amdgcn_mfma_f32_16x16x32_f16(Af[2][2], B2.h, aN, 0, 0, 0);
        aR = __builtin_amdgcn_mfma_f32_16x16x32_f16(Af[0][3], B3.h, aR, 0, 0, 0);
        aZ = __builtin_amdgcn_mfma_f32_16x16x32_f16(Af[1][3], B3.h, aZ, 0, 0, 0);
        aN = __builtin_amdgcn_mfma_f32_16x16x32_f16(Af[2][3], B3.h, aN, 0, 0, 0);

        // gates for this lane's 4 units (redundant across n — identical)
#pragma unroll
        for (int r = 0; r < 4; ++r) {
            const float rg = __builtin_amdgcn_rcpf(1.f + __expf(-(gcr[r] + aR[r])));
            const float zg = __builtin_amdgcn_rcpf(1.f + __expf(-(gcz[r] + aZ[r])));
            float tt = gcn[r] + rg * (aN[r] + b_n4[r]);
            tt = fminf(fmaxf(tt, -15.f), 15.f);
            const float e  = __expf(-2.f * tt);
            const float ng = (1.f - e) * __builtin_amdgcn_rcpf(1.f + e);
            hq[r] = (1.f - zg) * ng + zg * hq[r];
        }

        if (n == 0) {
            uint2 w2;
            w2.x = pack_f16(hq[0], hq[1]);
            w2.y = pack_f16(hq[2], hq[3]);
            *(uint2*)&h_lds[cur ^ 1][u4 >> 1] = w2;
            *(f32x4*)op = hq;
        }
        gcr = pr + b_r4; gcz = pz + b_z4; gcn = pn;
        gp = gpn; op += oinc;
        __syncthreads();
    };

    for (int step = 0; step < SEQ; step += 2) { body(0); body(1); }
}

// ---------------------------------------------------------------------------
// Kernel 3: logits + softmax -> LDS; Viterbi forward with pure-DPP allgather
// (8-padded states mirrored across all 64 lanes, row_ror rotations — no LDS
// on the serial chain); chunked backtrack. One block, 384 threads.
// ---------------------------------------------------------------------------
__global__ __launch_bounds__(G3) void k_out_viterbi(
    const float* __restrict__ fwd, const float* __restrict__ bwd,
    const float* __restrict__ W_out, const float* __restrict__ b_out,
    const float* __restrict__ trans, float* __restrict__ out)
{
    __shared__ float p_lds[(SEQ + 1) * NS];           // +1 pad row for prefetch
    __shared__ unsigned char bp_lds[(SEQ - 1) * NS];
    __shared__ unsigned char cmap[32 * NS];
    __shared__ int bstate[32];
    __shared__ int s_last;

    const int tid = threadIdx.x;

    // ---- Phase A: logits + softmax per timestep ----
    for (int t = tid; t < SEQ; t += G3) {
        const float4* f4 = (const float4*)(fwd + (size_t)t * HID);
        const float4* b4 = (const float4*)(bwd + (size_t)t * HID);
        float lg[NS];
#pragma unroll
        for (int s = 0; s < NS; ++s) lg[s] = b_out[s];
#pragma unroll 4
        for (int k4 = 0; k4 < 32; ++k4) {
            const float4 fv = f4[k4];
            const float4 bv = b4[k4];
#pragma unroll
            for (int s = 0; s < NS; ++s) {
                const float4 wf = ((const float4*)(W_out + s * 256))[k4];
                const float4 wb = ((const float4*)(W_out + s * 256 + HID))[k4];
                lg[s] += wf.x * fv.x + wf.y * fv.y + wf.z * fv.z + wf.w * fv.w
                       + wb.x * bv.x + wb.y * bv.y + wb.z * bv.z + wb.w * bv.w;
            }
        }
        float m = lg[0];
#pragma unroll
        for (int s = 1; s < NS; ++s) m = fmaxf(m, lg[s]);
        float sum = 0.f;
#pragma unroll
        for (int s = 0; s < NS; ++s) { lg[s] = __expf(lg[s] - m); sum += lg[s]; }
        const float inv = 1.f / sum;
#pragma unroll
        for (int s = 0; s < NS; ++s) p_lds[t * NS + s] = lg[s] * inv;
    }
    __syncthreads();

    // ---- Phase B: serial Viterbi forward, pure-DPP (wave 0, all 64 lanes,
    // state sj = lane&7 mirrored; states 6,7 are -inf dummies) ----
    if (tid < 64) {
        const int sj = tid & 7;
        const bool real = (sj < NS);
        const int jc = real ? sj : 0;
        float tcs[8]; int isv[8];
#pragma unroll
        for (int s = 0; s < 8; ++s) {
            const int i = (sj + s) & 7;
            isv[s] = i;
            tcs[s] = (real && i < NS) ? trans[i * NS + sj] : 0.f;
        }
        float tr = real ? p_lds[sj] : -3.0e38f;
        float pv = p_lds[NS + jc];

        for (int t = 1; t < SEQ; ++t) {
            // 7 independent rotations: lane gets tr of state (sj+s)&7
            const float r1 = dpp_movf<0x121>(tr);
            const float r2 = dpp_movf<0x122>(tr);
            const float r3 = dpp_movf<0x123>(tr);
            const float r4 = dpp_movf<0x124>(tr);
            const float r5 = dpp_movf<0x125>(tr);
            const float r6 = dpp_movf<0x126>(tr);
            const float r7 = dpp_movf<0x127>(tr);
            const float pnext = p_lds[(t + 1) * NS + jc];  // pad row at end
            const float v0 = tr + tcs[0];
            const float v1 = r1 + tcs[1];
            const float v2 = r2 + tcs[2];
            const float v3 = r3 + tcs[3];
            const float v4 = r4 + tcs[4];
            const float v5 = r5 + tcs[5];
            const float v6 = r6 + tcs[6];
            const float v7 = r7 + tcs[7];
            const float best = fmaxf(fmaxf(fmaxf(v0, v1), fmaxf(v2, v3)),
                                     fmaxf(fmaxf(v4, v5), fmaxf(v6, v7)));
            const float trn = pv + best;
            // first-max == smallest source index among ties (dummies never tie)
            int bi = 7;
            bi = min(bi, (v0 == best) ? isv[0] : 7);
            bi = min(bi, (v1 == best) ? isv[1] : 7);
            bi = min(bi, (v2 == best) ? isv[2] : 7);
            bi = min(bi, (v3 == best) ? isv[3] : 7);
            bi = min(bi, (v4 == best) ? isv[4] : 7);
            bi = min(bi, (v5 == best) ? isv[5] : 7);
            bi = min(bi, (v6 == best) ? isv[6] : 7);
            bi = min(bi, (v7 == best) ? isv[7] : 7);
            if (tid < NS) bp_lds[(t - 1) * NS + sj] = (unsigned char)bi;
            tr = real ? trn : -3.0e38f;
            pv = pnext;
        }
        // final argmax over the 6 trellis values (same rotation trick)
        {
            const float r1 = dpp_movf<0x121>(tr);
            const float r2 = dpp_movf<0x122>(tr);
            const float r3 = dpp_movf<0x123>(tr);
            const float r4 = dpp_movf<0x124>(tr);
            const float r5 = dpp_movf<0x125>(tr);
            const float r6 = dpp_movf<0x126>(tr);
            const float r7 = dpp_movf<0x127>(tr);
            const float best = fmaxf(fmaxf(fmaxf(tr, r1), fmaxf(r2, r3)),
                                     fmaxf(fmaxf(r4, r5), fmaxf(r6, r7)));
            int bi = 7;
            bi = min(bi, (tr == best) ? isv[0] : 7);
            bi = min(bi, (r1 == best) ? isv[1] : 7);
            bi = min(bi, (r2 == best) ? isv[2] : 7);
            bi = min(bi, (r3 == best) ? isv[3] : 7);
            bi = min(bi, (r4 == best) ? isv[4] : 7);
            bi = min(bi, (r5 == best) ? isv[5] : 7);
            bi = min(bi, (r6 == best) ? isv[6] : 7);
            bi = min(bi, (r7 == best) ? isv[7] : 7);
            if (tid == 0) { out[0] = best; s_last = bi; }
        }
    }
    __syncthreads();

    // ---- Phase C1: per-chunk backpointer composition (192 walkers) ----
    if (tid < 32 * NS) {
        const int c = tid / NS, s0 = tid % NS;
        const int hi = (c == 31) ? (SEQ - 1) : 64 * (c + 1);
        const int lo = 64 * c;
        int s = s0;
        for (int tau = hi; tau > lo; --tau) s = bp_lds[(tau - 1) * NS + s];
        cmap[c * NS + s0] = (unsigned char)s;
    }
    __syncthreads();

    // ---- Phase C2: serial splice over 32 chunk boundaries ----
    if (tid == 0) {
        int s = s_last;
        for (int c = 31; c >= 0; --c) {
            s = cmap[c * NS + s];
            bstate[c] = s;
        }
    }
    __syncthreads();

    // ---- Phase C3: parallel emit (32 chunks re-walk) ----
    if (tid < 32) {
        const int c = tid;
        const int hi = (c == 31) ? (SEQ - 1) : 64 * (c + 1);
        const int lo = 64 * c;
        int s = (c == 31) ? s_last : bstate[c + 1];
        for (int tau = hi; tau > lo; --tau) {
            out[1 + tau] = (float)s;
            s = bp_lds[(tau - 1) * NS + s];
        }
        if (c == 0) out[1] = (float)s;   // time 0
    }
}

// ---------------------------------------------------------------------------
extern "C" void kernel_launch(void* const* d_in, const int* in_sizes, int n_in,
                              void* d_out, int out_size, void* d_ws, size_t ws_size,
                              hipStream_t stream)
{
    (void)in_sizes; (void)n_in; (void)out_size; (void)ws_size;

    const int*   sent  = (const int*)  d_in[0];
    const float* emb   = (const float*)d_in[1];
    const float* h0    = (const float*)d_in[2];
    const float* Wf_ih = (const float*)d_in[3];
    const float* Wf_hh = (const float*)d_in[4];
    const float* bf_ih = (const float*)d_in[5];
    const float* bf_hh = (const float*)d_in[6];
    const float* Wb_ih = (const float*)d_in[7];
    const float* Wb_hh = (const float*)d_in[8];
    const float* bb_ih = (const float*)d_in[9];
    const float* bb_hh = (const float*)d_in[10];
    const float* W_out = (const float*)d_in[11];
    const float* b_out = (const float*)d_in[12];
    const float* trans = (const float*)d_in[13];
    float* out = (float*)d_out;

    // workspace layout (floats): gi_f[SEQ*G3] | gi_b[SEQ*G3] | fwd[SEQ*HID] | bwd[SEQ*HID]
    float* ws   = (float*)d_ws;
    float* gi_f = ws;
    float* gi_b = ws + (size_t)SEQ * G3;
    float* fwdb = ws + (size_t)2 * SEQ * G3;
    float* bwdb = fwdb + (size_t)SEQ * HID;

    k_input_proj<<<SEQ / 4, G3, 0, stream>>>(sent, emb, Wf_ih, bf_ih, Wb_ih, bb_ih, gi_f, gi_b);
    k_recur<<<2, 512, 0, stream>>>(gi_f, gi_b, Wf_hh, bf_hh, Wb_hh, bb_hh, h0, fwdb, bwdb);
    k_out_viterbi<<<1, G3, 0, stream>>>(fwdb, bwdb, W_out, b_out, trans, out);
}

// Round 8
// 1425.371 us; speedup vs baseline: 1.2634x; 1.2634x over previous
//
#include <hip/hip_runtime.h>
#include <math.h>
#include <stdint.h>

// Problem constants (from reference setup_inputs)
constexpr int SEQ   = 2048;  // T
constexpr int BATCH = 64;    // B
constexpr int EMB   = 100;   // E
constexpr int HID   = 128;   // H
constexpr int G3    = 384;   // 3*H
constexpr int NS    = 6;     // S (CRF states)
constexpr int BSEL  = 63;    // only batch row 63 affects the output

#define KEEPI(v) asm volatile("" : "+v"(v))

typedef _Float16 f16x2 __attribute__((ext_vector_type(2)));

#if defined(__has_builtin)
#if __has_builtin(__builtin_amdgcn_fdot2)
#define HAVE_FDOT2 1
#endif
#endif

// Packed f16 dot2 with fp32 accumulate (products exact in f32).
__device__ __forceinline__ float dot2(uint32_t w, uint32_t h, float acc) {
#ifdef HAVE_FDOT2
    return __builtin_amdgcn_fdot2(__builtin_bit_cast(f16x2, w),
                                  __builtin_bit_cast(f16x2, h), acc, false);
#else
    f16x2 wv = __builtin_bit_cast(f16x2, w), hv = __builtin_bit_cast(f16x2, h);
    acc = fmaf((float)wv.x, (float)hv.x, acc);
    return fmaf((float)wv.y, (float)hv.y, acc);
#endif
}

__device__ __forceinline__ uint32_t pack_f16(float a, float b) {
    f16x2 p; p.x = (_Float16)a; p.y = (_Float16)b;
    return __builtin_bit_cast(uint32_t, p);
}

__device__ __forceinline__ float half_sel(uint32_t p, int hi) {
    const f16x2 v = __builtin_bit_cast(f16x2, p);
    return hi ? (float)v.y : (float)v.x;
}

// DPP cross-lane add within quad: xor1 = 0xB1, xor2 = 0x4E
template <int CTRL>
__device__ __forceinline__ float dpp_add(float x) {
    int v = __builtin_amdgcn_update_dpp(0, __float_as_int(x), CTRL, 0xF, 0xF, true);
    return x + __int_as_float(v);
}
// quad broadcast from lane c of each quad: ctrl = c*0x55
template <int CTRL>
__device__ __forceinline__ uint32_t dpp_bcast(uint32_t x) {
    return (uint32_t)__builtin_amdgcn_update_dpp(0, (int)x, CTRL, 0xF, 0xF, true);
}

__device__ __forceinline__ float bperm_f(int srclane, float x) {
    return __int_as_float(__builtin_amdgcn_ds_bpermute(srclane * 4, __float_as_int(x)));
}

// ---------------------------------------------------------------------------
// Kernel 1: embedding lookup + input projection for batch row 63 only.
// 4 timesteps per block; emits gi TRANSPOSED as packed f16 unit-pairs:
//   gi_t[(g*64 + u2)*SEQ + t] = pack(gi[t][g*128+2*u2], gi[t][g*128+2*u2+1])
// so k_recur can batch-load 8 timesteps per window (contiguous in t).
// ---------------------------------------------------------------------------
__global__ __launch_bounds__(G3) void k_input_proj(
    const int* __restrict__ sent, const float* __restrict__ emb,
    const float* __restrict__ Wf_ih, const float* __restrict__ bf_ih,
    const float* __restrict__ Wb_ih, const float* __restrict__ bb_ih,
    uint32_t* __restrict__ gi_ft, uint32_t* __restrict__ gi_bt)
{
    const int tb = blockIdx.x * 4;
    const int j  = threadIdx.x;           // 0..383 = weight row (g*128 + u)
    __shared__ __align__(16) float x_s[4][EMB];

    int toks[4];
#pragma unroll
    for (int tt = 0; tt < 4; ++tt) toks[tt] = sent[BSEL * SEQ + tb + tt];
    if (j < EMB) {
#pragma unroll
        for (int tt = 0; tt < 4; ++tt)
            x_s[tt][j] = emb[(size_t)toks[tt] * EMB + j];
    }
    __syncthreads();

    float4 wf4[25], wb4[25];
    const float4* wfp = (const float4*)(Wf_ih + (size_t)j * EMB);
    const float4* wbp = (const float4*)(Wb_ih + (size_t)j * EMB);
#pragma unroll
    for (int m = 0; m < 25; ++m) { wf4[m] = wfp[m]; wb4[m] = wbp[m]; }
    const float bf = bf_ih[j], bb = bb_ih[j];

    const int g  = j >> 7;
    const int u  = j & 127;
    const int u2 = u >> 1;
    const size_t orow = ((size_t)(g * 64 + u2)) * SEQ;

#pragma unroll
    for (int tt = 0; tt < 4; ++tt) {
        const float4* xs = (const float4*)(x_s[tt]);
        float af = 0.f, ab = 0.f;
#pragma unroll
        for (int m = 0; m < 25; ++m) {
            const float4 xv = xs[m];
            af = fmaf(wf4[m].x, xv.x, af); af = fmaf(wf4[m].y, xv.y, af);
            af = fmaf(wf4[m].z, xv.z, af); af = fmaf(wf4[m].w, xv.w, af);
            ab = fmaf(wb4[m].x, xv.x, ab); ab = fmaf(wb4[m].y, xv.y, ab);
            ab = fmaf(wb4[m].z, xv.z, ab); ab = fmaf(wb4[m].w, xv.w, ab);
        }
        const float vf = af + bf;
        const float vb = ab + bb;
        // pair units (u even with u+1) — partner is adjacent lane
        const float vf_n = __shfl_xor(vf, 1);
        const float vb_n = __shfl_xor(vb, 1);
        if ((u & 1) == 0) {
            gi_ft[orow + tb + tt] = pack_f16(vf, vf_n);
            gi_bt[orow + tb + tt] = pack_f16(vb, vb_n);
        }
    }
}

// ---------------------------------------------------------------------------
// Kernel 2: GRU recurrence. One block (512 thr) per direction.
// Thread = (unit u = wv*16 + (lane>>2), kc = lane&3 -> 32-col chunk).
// 48 packed f16 weights/thread (rows r,z,n of u over cols [32kc,32kc+32)).
// Per step: 4 broadcast ds_read_b128 (h as f16 pairs), 48 dot2, 2-stage
// quad DPP reduce, gates on all 4 quad lanes (identical), kc==0 writes h.
// KEY: gi is loaded once per 8-step window (2 slots per kc lane, distributed
// at each step via compile-time quad_perm broadcast) and h outputs are
// buffered and stored once per window — so the per-step __syncthreads has
// no outstanding global ops to drain (the vmcnt(0)-before-s_barrier drain
// was the ~950 cyc/step invariant of R2-R6). One ~HBM-latency drain per
// 8 steps instead of per step.
// ---------------------------------------------------------------------------
template <int DIR>
__device__ void gru_run(const uint32_t* __restrict__ git,
                        const float* __restrict__ Whh,
                        const float* __restrict__ bhh,
                        const float* __restrict__ h0,
                        float* __restrict__ outs)
{
    const int tid  = threadIdx.x;
    const int lane = tid & 63;
    const int wv   = tid >> 6;            // 0..7
    const int kc   = lane & 3;            // 32-col chunk
    const int ug   = lane >> 2;           // 0..15
    const int u    = wv * 16 + ug;        // unit 0..127
    const int u2   = u >> 1;
    const int halfu = u & 1;

    // --- weights: rows {u, 128+u, 256+u}, cols [32kc, 32kc+32), f16-packed
    uint32_t Wp0[16], Wp1[16], Wp2[16];
    {
        const float* r0 = Whh + (size_t)u * HID + 32 * kc;
        const float* r1 = Whh + (size_t)(HID + u) * HID + 32 * kc;
        const float* r2 = Whh + (size_t)(2 * HID + u) * HID + 32 * kc;
#pragma unroll
        for (int m4 = 0; m4 < 8; ++m4) {
            const float4 a = ((const float4*)r0)[m4];
            const float4 b = ((const float4*)r1)[m4];
            const float4 c = ((const float4*)r2)[m4];
            Wp0[2 * m4] = pack_f16(a.x, a.y); Wp0[2 * m4 + 1] = pack_f16(a.z, a.w);
            Wp1[2 * m4] = pack_f16(b.x, b.y); Wp1[2 * m4 + 1] = pack_f16(b.z, b.w);
            Wp2[2 * m4] = pack_f16(c.x, c.y); Wp2[2 * m4 + 1] = pack_f16(c.z, c.w);
        }
#pragma unroll
        for (int m = 0; m < 16; ++m) { KEEPI(Wp0[m]); KEEPI(Wp1[m]); KEEPI(Wp2[m]); }
    }

    const float b_r = bhh[u];
    const float b_z = bhh[HID + u];
    const float b_n = bhh[2 * HID + u];

    float h_u = h0[(size_t)DIR * BATCH * HID + BSEL * HID + u];

    // gi row bases (packed unit pairs, t-contiguous)
    const uint32_t* grb = git + (size_t)(0 * 64 + u2) * SEQ;
    const uint32_t* gzb = git + (size_t)(1 * 64 + u2) * SEQ;
    const uint32_t* gnb = git + (size_t)(2 * 64 + u2) * SEQ;

    __shared__ __align__(16) uint32_t h_lds[2][HID / 2];
    if (tid < HID / 2) {
        const float2 hh = *(const float2*)(h0 + (size_t)DIR * BATCH * HID + BSEL * HID + 2 * tid);
        h_lds[0][tid] = pack_f16(hh.x, hh.y);
    }

    // window-0 gi: lane kc holds in-window t-slots kc and kc+4
    uint32_t gcu[2][3];
    {
        const int bt = DIR ? (SEQ - 8) : 0;
        gcu[0][0] = grb[bt + kc];     gcu[0][1] = gzb[bt + kc];     gcu[0][2] = gnb[bt + kc];
        gcu[1][0] = grb[bt + 4 + kc]; gcu[1][1] = gzb[bt + 4 + kc]; gcu[1][2] = gnb[bt + 4 + kc];
    }
    __syncthreads();   // drains prologue loads once

    float hs0 = 0, hs1 = 0, hs2 = 0, hs3 = 0, hs4 = 0, hs5 = 0, hs6 = 0, hs7 = 0;

#define GRU_STEP(I, KIDX) do {                                                 \
    const uint4* hb4 = (const uint4*)(h_lds[(I) & 1]);                         \
    const uint4 hq0 = hb4[4 * kc + 0], hq1 = hb4[4 * kc + 1];                  \
    const uint4 hq2 = hb4[4 * kc + 2], hq3 = hb4[4 * kc + 3];                  \
    const uint32_t hw[16] = {hq0.x, hq0.y, hq0.z, hq0.w,                       \
                             hq1.x, hq1.y, hq1.z, hq1.w,                       \
                             hq2.x, hq2.y, hq2.z, hq2.w,                       \
                             hq3.x, hq3.y, hq3.z, hq3.w};                      \
    float ar = 0.f, az = 0.f, an = 0.f;                                        \
    _Pragma("unroll")                                                          \
    for (int m = 0; m < 16; ++m) {                                             \
        ar = dot2(Wp0[m], hw[m], ar);                                          \
        az = dot2(Wp1[m], hw[m], az);                                          \
        an = dot2(Wp2[m], hw[m], an);                                          \
    }                                                                          \
    ar = dpp_add<0x4E>(dpp_add<0xB1>(ar));                                     \
    az = dpp_add<0x4E>(dpp_add<0xB1>(az));                                     \
    an = dpp_add<0x4E>(dpp_add<0xB1>(an));                                     \
    const uint32_t gur = dpp_bcast<((KIDX) & 3) * 0x55>(gcu[(KIDX) >> 2][0]);  \
    const uint32_t guz = dpp_bcast<((KIDX) & 3) * 0x55>(gcu[(KIDX) >> 2][1]);  \
    const uint32_t gun = dpp_bcast<((KIDX) & 3) * 0x55>(gcu[(KIDX) >> 2][2]);  \
    const float gr = half_sel(gur, halfu) + b_r;                               \
    const float gz = half_sel(guz, halfu) + b_z;                               \
    const float gn = half_sel(gun, halfu);                                     \
    const float rg = __builtin_amdgcn_rcpf(1.f + __expf(-(gr + ar)));          \
    const float zg = __builtin_amdgcn_rcpf(1.f + __expf(-(gz + az)));          \
    float ttv = gn + rg * (an + b_n);                                          \
    ttv = fminf(fmaxf(ttv, -15.f), 15.f);                                      \
    const float e = __expf(-2.f * ttv);                                        \
    const float ng = (1.f - e) * __builtin_amdgcn_rcpf(1.f + e);               \
    h_u = (1.f - zg) * ng + zg * h_u;                                          \
    if (kc == 0) {                                                             \
        hs##I = h_u;                                                           \
        ((_Float16*)(h_lds[((I) & 1) ^ 1]))[u] = (_Float16)h_u;                \
    }                                                                          \
    __syncthreads();                                                           \
} while (0)

    constexpr int NW = SEQ / 8;
    for (int w = 0; w < NW; ++w) {
        GRU_STEP(0, (DIR ? 7 : 0));
        GRU_STEP(1, (DIR ? 6 : 1));
        GRU_STEP(2, (DIR ? 5 : 2));
        GRU_STEP(3, (DIR ? 4 : 3));
        GRU_STEP(4, (DIR ? 3 : 4));
        GRU_STEP(5, (DIR ? 2 : 5));
        GRU_STEP(6, (DIR ? 1 : 6));
        GRU_STEP(7, (DIR ? 0 : 7));

        // window-end writeback (kc==0 lanes: this unit's 8 timesteps)
        if (kc == 0) {
            const int t0 = DIR ? (SEQ - 1 - 8 * w) : 8 * w;
            const int ti = DIR ? -1 : 1;
            outs[(size_t)(t0 + 0 * ti) * HID + u] = hs0;
            outs[(size_t)(t0 + 1 * ti) * HID + u] = hs1;
            outs[(size_t)(t0 + 2 * ti) * HID + u] = hs2;
            outs[(size_t)(t0 + 3 * ti) * HID + u] = hs3;
            outs[(size_t)(t0 + 4 * ti) * HID + u] = hs4;
            outs[(size_t)(t0 + 5 * ti) * HID + u] = hs5;
            outs[(size_t)(t0 + 6 * ti) * HID + u] = hs6;
            outs[(size_t)(t0 + 7 * ti) * HID + u] = hs7;
        }
        // next-window gi (drained once at next window's first barrier)
        if (w + 1 < NW) {
            const int bt = DIR ? (SEQ - 8 - 8 * (w + 1)) : (8 * (w + 1));
            gcu[0][0] = grb[bt + kc];     gcu[0][1] = gzb[bt + kc];     gcu[0][2] = gnb[bt + kc];
            gcu[1][0] = grb[bt + 4 + kc]; gcu[1][1] = gzb[bt + 4 + kc]; gcu[1][2] = gnb[bt + 4 + kc];
        }
    }
#undef GRU_STEP
}

__global__ __launch_bounds__(512, 1) void k_recur(
    const uint32_t* __restrict__ gi_ft, const uint32_t* __restrict__ gi_bt,
    const float* __restrict__ Wf_hh, const float* __restrict__ bf_hh,
    const float* __restrict__ Wb_hh, const float* __restrict__ bb_hh,
    const float* __restrict__ h0,
    float* __restrict__ fwd, float* __restrict__ bwd)
{
    if (blockIdx.x == 0) gru_run<0>(gi_ft, Wf_hh, bf_hh, h0, fwd);
    else                 gru_run<1>(gi_bt, Wb_hh, bb_hh, h0, bwd);
}

// ---------------------------------------------------------------------------
// Kernel 3: logits + softmax -> LDS; serial Viterbi forward with batched
// ds_bpermute allgather + fmax tree / equality first-argmax (exact, R6-
// verified absmax 0.0); chunked backtrack. One block, 384 threads.
// ---------------------------------------------------------------------------
__global__ __launch_bounds__(G3) void k_out_viterbi(
    const float* __restrict__ fwd, const float* __restrict__ bwd,
    const float* __restrict__ W_out, const float* __restrict__ b_out,
    const float* __restrict__ trans, float* __restrict__ out)
{
    __shared__ float p_lds[(SEQ + 1) * NS];           // +1 pad row for prefetch
    __shared__ unsigned char bp_lds[(SEQ - 1) * NS];
    __shared__ unsigned char cmap[32 * NS];
    __shared__ int bstate[32];
    __shared__ int s_last;

    const int tid = threadIdx.x;

    // ---- Phase A: logits + softmax per timestep ----
    for (int t = tid; t < SEQ; t += G3) {
        const float4* f4 = (const float4*)(fwd + (size_t)t * HID);
        const float4* b4 = (const float4*)(bwd + (size_t)t * HID);
        float lg[NS];
#pragma unroll
        for (int s = 0; s < NS; ++s) lg[s] = b_out[s];
#pragma unroll 4
        for (int k4 = 0; k4 < 32; ++k4) {
            const float4 fv = f4[k4];
            const float4 bv = b4[k4];
#pragma unroll
            for (int s = 0; s < NS; ++s) {
                const float4 wf = ((const float4*)(W_out + s * 256))[k4];
                const float4 wb = ((const float4*)(W_out + s * 256 + HID))[k4];
                lg[s] += wf.x * fv.x + wf.y * fv.y + wf.z * fv.z + wf.w * fv.w
                       + wb.x * bv.x + wb.y * bv.y + wb.z * bv.z + wb.w * bv.w;
            }
        }
        float m = lg[0];
#pragma unroll
        for (int s = 1; s < NS; ++s) m = fmaxf(m, lg[s]);
        float sum = 0.f;
#pragma unroll
        for (int s = 0; s < NS; ++s) { lg[s] = __expf(lg[s] - m); sum += lg[s]; }
        const float inv = 1.f / sum;
#pragma unroll
        for (int s = 0; s < NS; ++s) p_lds[t * NS + s] = lg[s] * inv;
    }
    __syncthreads();

    // ---- Phase B: exact serial Viterbi forward (wave 0, lanes 0..5) ----
    if (tid < 64) {
        const int j = tid;
        const bool act = (j < NS);
        const int jc = act ? j : 0;
        float tc0 = act ? trans[0 * NS + j] : 0.f;
        float tc1 = act ? trans[1 * NS + j] : 0.f;
        float tc2 = act ? trans[2 * NS + j] : 0.f;
        float tc3 = act ? trans[3 * NS + j] : 0.f;
        float tc4 = act ? trans[4 * NS + j] : 0.f;
        float tc5 = act ? trans[5 * NS + j] : 0.f;
        float tr = act ? p_lds[j] : -3.0e38f;
        float pv = p_lds[NS + jc];

        for (int t = 1; t < SEQ; ++t) {
            const float v0 = bperm_f(0, tr) + tc0;
            const float v1 = bperm_f(1, tr) + tc1;
            const float v2 = bperm_f(2, tr) + tc2;
            const float v3 = bperm_f(3, tr) + tc3;
            const float v4 = bperm_f(4, tr) + tc4;
            const float v5 = bperm_f(5, tr) + tc5;
            const float pnext = p_lds[(t + 1) * NS + jc];
            const float best = fmaxf(fmaxf(fmaxf(v0, v1), v2),
                                     fmaxf(fmaxf(v3, v4), v5));
            const float trn = pv + best;
            int bi = 5;
            bi = (v4 == best) ? 4 : bi;
            bi = (v3 == best) ? 3 : bi;
            bi = (v2 == best) ? 2 : bi;
            bi = (v1 == best) ? 1 : bi;
            bi = (v0 == best) ? 0 : bi;
            if (act) bp_lds[(t - 1) * NS + j] = (unsigned char)bi;
            tr = act ? trn : tr;
            pv = pnext;
        }
        const float f0 = bperm_f(0, tr);
        const float f1 = bperm_f(1, tr);
        const float f2 = bperm_f(2, tr);
        const float f3 = bperm_f(3, tr);
        const float f4 = bperm_f(4, tr);
        const float f5 = bperm_f(5, tr);
        const float best = fmaxf(fmaxf(fmaxf(f0, f1), f2),
                                 fmaxf(fmaxf(f3, f4), f5));
        int bi = 5;
        bi = (f4 == best) ? 4 : bi;
        bi = (f3 == best) ? 3 : bi;
        bi = (f2 == best) ? 2 : bi;
        bi = (f1 == best) ? 1 : bi;
        bi = (f0 == best) ? 0 : bi;
        if (tid == 0) { out[0] = best; s_last = bi; }
    }
    __syncthreads();

    // ---- Phase C1: per-chunk backpointer composition (192 walkers) ----
    if (tid < 32 * NS) {
        const int c = tid / NS, s0 = tid % NS;
        const int hi = (c == 31) ? (SEQ - 1) : 64 * (c + 1);
        const int lo = 64 * c;
        int s = s0;
        for (int tau = hi; tau > lo; --tau) s = bp_lds[(tau - 1) * NS + s];
        cmap[c * NS + s0] = (unsigned char)s;
    }
    __syncthreads();

    // ---- Phase C2: serial splice over 32 chunk boundaries ----
    if (tid == 0) {
        int s = s_last;
        for (int c = 31; c >= 0; --c) {
            s = cmap[c * NS + s];
            bstate[c] = s;
        }
    }
    __syncthreads();

    // ---- Phase C3: parallel emit (32 chunks re-walk) ----
    if (tid < 32) {
        const int c = tid;
        const int hi = (c == 31) ? (SEQ - 1) : 64 * (c + 1);
        const int lo = 64 * c;
        int s = (c == 31) ? s_last : bstate[c + 1];
        for (int tau = hi; tau > lo; --tau) {
            out[1 + tau] = (float)s;
            s = bp_lds[(tau - 1) * NS + s];
        }
        if (c == 0) out[1] = (float)s;   // time 0
    }
}

// ---------------------------------------------------------------------------
extern "C" void kernel_launch(void* const* d_in, const int* in_sizes, int n_in,
                              void* d_out, int out_size, void* d_ws, size_t ws_size,
                              hipStream_t stream)
{
    (void)in_sizes; (void)n_in; (void)out_size; (void)ws_size;

    const int*   sent  = (const int*)  d_in[0];
    const float* emb   = (const float*)d_in[1];
    const float* h0    = (const float*)d_in[2];
    const float* Wf_ih = (const float*)d_in[3];
    const float* Wf_hh = (const float*)d_in[4];
    const float* bf_ih = (const float*)d_in[5];
    const float* bf_hh = (const float*)d_in[6];
    const float* Wb_ih = (const float*)d_in[7];
    const float* Wb_hh = (const float*)d_in[8];
    const float* bb_ih = (const float*)d_in[9];
    const float* bb_hh = (const float*)d_in[10];
    const float* W_out = (const float*)d_in[11];
    const float* b_out = (const float*)d_in[12];
    const float* trans = (const float*)d_in[13];
    float* out = (float*)d_out;

    // workspace layout (floats):
    //   [0, SEQ*G3)            : gi_ft + gi_bt (packed f16 uints, SEQ*192 each)
    //   [2*SEQ*G3, +SEQ*HID)   : fwd
    //   next SEQ*HID           : bwd
    float*    ws    = (float*)d_ws;
    uint32_t* gi_ft = (uint32_t*)ws;
    uint32_t* gi_bt = gi_ft + (size_t)SEQ * 192;
    float*    fwdb  = ws + (size_t)2 * SEQ * G3;
    float*    bwdb  = fwdb + (size_t)SEQ * HID;

    k_input_proj<<<SEQ / 4, G3, 0, stream>>>(sent, emb, Wf_ih, bf_ih, Wb_ih, bb_ih, gi_ft, gi_bt);
    k_recur<<<2, 512, 0, stream>>>(gi_ft, gi_bt, Wf_hh, bf_hh, Wb_hh, bb_hh, h0, fwdb, bwdb);
    k_out_viterbi<<<1, G3, 0, stream>>>(fwdb, bwdb, W_out, b_out, trans, out);
}

// Round 10
// 1161.467 us; speedup vs baseline: 1.5505x; 1.2272x over previous
//
#include <hip/hip_runtime.h>
#include <math.h>
#include <stdint.h>

// Problem constants (from reference setup_inputs)
constexpr int SEQ   = 2048;  // T
constexpr int BATCH = 64;    // B
constexpr int EMB   = 100;   // E
constexpr int HID   = 128;   // H
constexpr int G3    = 384;   // 3*H
constexpr int NS    = 6;     // S (CRF states)
constexpr int BSEL  = 63;    // only batch row 63 affects the output

#define KEEPI(v) asm volatile("" : "+v"(v))

typedef _Float16 f16x2 __attribute__((ext_vector_type(2)));

#if defined(__has_builtin)
#if __has_builtin(__builtin_amdgcn_fdot2)
#define HAVE_FDOT2 1
#endif
#endif

__device__ __forceinline__ float dot2(uint32_t w, uint32_t h, float acc) {
#ifdef HAVE_FDOT2
    return __builtin_amdgcn_fdot2(__builtin_bit_cast(f16x2, w),
                                  __builtin_bit_cast(f16x2, h), acc, false);
#else
    f16x2 wv = __builtin_bit_cast(f16x2, w), hv = __builtin_bit_cast(f16x2, h);
    acc = fmaf((float)wv.x, (float)hv.x, acc);
    return fmaf((float)wv.y, (float)hv.y, acc);
#endif
}

__device__ __forceinline__ uint32_t pack_f16(float a, float b) {
    f16x2 p; p.x = (_Float16)a; p.y = (_Float16)b;
    return __builtin_bit_cast(uint32_t, p);
}

__device__ __forceinline__ float half_sel(uint32_t p, int hi) {
    const f16x2 v = __builtin_bit_cast(f16x2, p);
    return hi ? (float)v.y : (float)v.x;
}

template <int CTRL>
__device__ __forceinline__ float dpp_add(float x) {
    int v = __builtin_amdgcn_update_dpp(0, __float_as_int(x), CTRL, 0xF, 0xF, true);
    return x + __int_as_float(v);
}
template <int CTRL>
__device__ __forceinline__ uint32_t dpp_bcast(uint32_t x) {
    return (uint32_t)__builtin_amdgcn_update_dpp(0, (int)x, CTRL, 0xF, 0xF, true);
}

// ---------------------------------------------------------------------------
// Kernel 1: embedding lookup + input projection for batch row 63 only.
// Emits gi TRANSPOSED as packed f16 unit-pairs (unchanged from R8).
// ---------------------------------------------------------------------------
__global__ __launch_bounds__(G3) void k_input_proj(
    const int* __restrict__ sent, const float* __restrict__ emb,
    const float* __restrict__ Wf_ih, const float* __restrict__ bf_ih,
    const float* __restrict__ Wb_ih, const float* __restrict__ bb_ih,
    uint32_t* __restrict__ gi_ft, uint32_t* __restrict__ gi_bt)
{
    const int tb = blockIdx.x * 4;
    const int j  = threadIdx.x;           // 0..383 = weight row (g*128 + u)
    __shared__ __align__(16) float x_s[4][EMB];

    int toks[4];
#pragma unroll
    for (int tt = 0; tt < 4; ++tt) toks[tt] = sent[BSEL * SEQ + tb + tt];
    if (j < EMB) {
#pragma unroll
        for (int tt = 0; tt < 4; ++tt)
            x_s[tt][j] = emb[(size_t)toks[tt] * EMB + j];
    }
    __syncthreads();

    float4 wf4[25], wb4[25];
    const float4* wfp = (const float4*)(Wf_ih + (size_t)j * EMB);
    const float4* wbp = (const float4*)(Wb_ih + (size_t)j * EMB);
#pragma unroll
    for (int m = 0; m < 25; ++m) { wf4[m] = wfp[m]; wb4[m] = wbp[m]; }
    const float bf = bf_ih[j], bb = bb_ih[j];

    const int g  = j >> 7;
    const int u  = j & 127;
    const int u2 = u >> 1;
    const size_t orow = ((size_t)(g * 64 + u2)) * SEQ;

#pragma unroll
    for (int tt = 0; tt < 4; ++tt) {
        const float4* xs = (const float4*)(x_s[tt]);
        float af = 0.f, ab = 0.f;
#pragma unroll
        for (int m = 0; m < 25; ++m) {
            const float4 xv = xs[m];
            af = fmaf(wf4[m].x, xv.x, af); af = fmaf(wf4[m].y, xv.y, af);
            af = fmaf(wf4[m].z, xv.z, af); af = fmaf(wf4[m].w, xv.w, af);
            ab = fmaf(wb4[m].x, xv.x, ab); ab = fmaf(wb4[m].y, xv.y, ab);
            ab = fmaf(wb4[m].z, xv.z, ab); ab = fmaf(wb4[m].w, xv.w, ab);
        }
        const float vf = af + bf;
        const float vb = ab + bb;
        const float vf_n = __shfl_xor(vf, 1);
        const float vb_n = __shfl_xor(vb, 1);
        if ((u & 1) == 0) {
            gi_ft[orow + tb + tt] = pack_f16(vf, vf_n);
            gi_bt[orow + tb + tt] = pack_f16(vb, vb_n);
        }
    }
}

// ---------------------------------------------------------------------------
// Kernel 2: GRU recurrence (R8-verified, unchanged). One block per dir;
// gi loaded once per 8-step window so the per-step barrier has no global
// ops to drain; h outputs buffered, stored once per window.
// ---------------------------------------------------------------------------
template <int DIR>
__device__ void gru_run(const uint32_t* __restrict__ git,
                        const float* __restrict__ Whh,
                        const float* __restrict__ bhh,
                        const float* __restrict__ h0,
                        float* __restrict__ outs)
{
    const int tid  = threadIdx.x;
    const int lane = tid & 63;
    const int wv   = tid >> 6;
    const int kc   = lane & 3;
    const int ug   = lane >> 2;
    const int u    = wv * 16 + ug;
    const int u2   = u >> 1;
    const int halfu = u & 1;

    uint32_t Wp0[16], Wp1[16], Wp2[16];
    {
        const float* r0 = Whh + (size_t)u * HID + 32 * kc;
        const float* r1 = Whh + (size_t)(HID + u) * HID + 32 * kc;
        const float* r2 = Whh + (size_t)(2 * HID + u) * HID + 32 * kc;
#pragma unroll
        for (int m4 = 0; m4 < 8; ++m4) {
            const float4 a = ((const float4*)r0)[m4];
            const float4 b = ((const float4*)r1)[m4];
            const float4 c = ((const float4*)r2)[m4];
            Wp0[2 * m4] = pack_f16(a.x, a.y); Wp0[2 * m4 + 1] = pack_f16(a.z, a.w);
            Wp1[2 * m4] = pack_f16(b.x, b.y); Wp1[2 * m4 + 1] = pack_f16(b.z, b.w);
            Wp2[2 * m4] = pack_f16(c.x, c.y); Wp2[2 * m4 + 1] = pack_f16(c.z, c.w);
        }
#pragma unroll
        for (int m = 0; m < 16; ++m) { KEEPI(Wp0[m]); KEEPI(Wp1[m]); KEEPI(Wp2[m]); }
    }

    const float b_r = bhh[u];
    const float b_z = bhh[HID + u];
    const float b_n = bhh[2 * HID + u];

    float h_u = h0[(size_t)DIR * BATCH * HID + BSEL * HID + u];

    const uint32_t* grb = git + (size_t)(0 * 64 + u2) * SEQ;
    const uint32_t* gzb = git + (size_t)(1 * 64 + u2) * SEQ;
    const uint32_t* gnb = git + (size_t)(2 * 64 + u2) * SEQ;

    __shared__ __align__(16) uint32_t h_lds[2][HID / 2];
    if (tid < HID / 2) {
        const float2 hh = *(const float2*)(h0 + (size_t)DIR * BATCH * HID + BSEL * HID + 2 * tid);
        h_lds[0][tid] = pack_f16(hh.x, hh.y);
    }

    uint32_t gcu[2][3];
    {
        const int bt = DIR ? (SEQ - 8) : 0;
        gcu[0][0] = grb[bt + kc];     gcu[0][1] = gzb[bt + kc];     gcu[0][2] = gnb[bt + kc];
        gcu[1][0] = grb[bt + 4 + kc]; gcu[1][1] = gzb[bt + 4 + kc]; gcu[1][2] = gnb[bt + 4 + kc];
    }
    __syncthreads();

    float hs0 = 0, hs1 = 0, hs2 = 0, hs3 = 0, hs4 = 0, hs5 = 0, hs6 = 0, hs7 = 0;

#define GRU_STEP(I, KIDX) do {                                                 \
    const uint4* hb4 = (const uint4*)(h_lds[(I) & 1]);                         \
    const uint4 hq0 = hb4[4 * kc + 0], hq1 = hb4[4 * kc + 1];                  \
    const uint4 hq2 = hb4[4 * kc + 2], hq3 = hb4[4 * kc + 3];                  \
    const uint32_t hw[16] = {hq0.x, hq0.y, hq0.z, hq0.w,                       \
                             hq1.x, hq1.y, hq1.z, hq1.w,                       \
                             hq2.x, hq2.y, hq2.z, hq2.w,                       \
                             hq3.x, hq3.y, hq3.z, hq3.w};                      \
    float ar = 0.f, az = 0.f, an = 0.f;                                        \
    _Pragma("unroll")                                                          \
    for (int m = 0; m < 16; ++m) {                                             \
        ar = dot2(Wp0[m], hw[m], ar);                                          \
        az = dot2(Wp1[m], hw[m], az);                                          \
        an = dot2(Wp2[m], hw[m], an);                                          \
    }                                                                          \
    ar = dpp_add<0x4E>(dpp_add<0xB1>(ar));                                     \
    az = dpp_add<0x4E>(dpp_add<0xB1>(az));                                     \
    an = dpp_add<0x4E>(dpp_add<0xB1>(an));                                     \
    const uint32_t gur = dpp_bcast<((KIDX) & 3) * 0x55>(gcu[(KIDX) >> 2][0]);  \
    const uint32_t guz = dpp_bcast<((KIDX) & 3) * 0x55>(gcu[(KIDX) >> 2][1]);  \
    const uint32_t gun = dpp_bcast<((KIDX) & 3) * 0x55>(gcu[(KIDX) >> 2][2]);  \
    const float gr = half_sel(gur, halfu) + b_r;                               \
    const float gz = half_sel(guz, halfu) + b_z;                               \
    const float gn = half_sel(gun, halfu);                                     \
    const float rg = __builtin_amdgcn_rcpf(1.f + __expf(-(gr + ar)));          \
    const float zg = __builtin_amdgcn_rcpf(1.f + __expf(-(gz + az)));          \
    float ttv = gn + rg * (an + b_n);                                          \
    ttv = fminf(fmaxf(ttv, -15.f), 15.f);                                      \
    const float e = __expf(-2.f * ttv);                                        \
    const float ng = (1.f - e) * __builtin_amdgcn_rcpf(1.f + e);               \
    h_u = (1.f - zg) * ng + zg * h_u;                                          \
    if (kc == 0) {                                                             \
        hs##I = h_u;                                                           \
        ((_Float16*)(h_lds[((I) & 1) ^ 1]))[u] = (_Float16)h_u;                \
    }                                                                          \
    __syncthreads();                                                           \
} while (0)

    constexpr int NW = SEQ / 8;
    for (int w = 0; w < NW; ++w) {
        GRU_STEP(0, (DIR ? 7 : 0));
        GRU_STEP(1, (DIR ? 6 : 1));
        GRU_STEP(2, (DIR ? 5 : 2));
        GRU_STEP(3, (DIR ? 4 : 3));
        GRU_STEP(4, (DIR ? 3 : 4));
        GRU_STEP(5, (DIR ? 2 : 5));
        GRU_STEP(6, (DIR ? 1 : 6));
        GRU_STEP(7, (DIR ? 0 : 7));

        if (kc == 0) {
            const int t0 = DIR ? (SEQ - 1 - 8 * w) : 8 * w;
            const int ti = DIR ? -1 : 1;
            outs[(size_t)(t0 + 0 * ti) * HID + u] = hs0;
            outs[(size_t)(t0 + 1 * ti) * HID + u] = hs1;
            outs[(size_t)(t0 + 2 * ti) * HID + u] = hs2;
            outs[(size_t)(t0 + 3 * ti) * HID + u] = hs3;
            outs[(size_t)(t0 + 4 * ti) * HID + u] = hs4;
            outs[(size_t)(t0 + 5 * ti) * HID + u] = hs5;
            outs[(size_t)(t0 + 6 * ti) * HID + u] = hs6;
            outs[(size_t)(t0 + 7 * ti) * HID + u] = hs7;
        }
        if (w + 1 < NW) {
            const int bt = DIR ? (SEQ - 8 - 8 * (w + 1)) : (8 * (w + 1));
            gcu[0][0] = grb[bt + kc];     gcu[0][1] = gzb[bt + kc];     gcu[0][2] = gnb[bt + kc];
            gcu[1][0] = grb[bt + 4 + kc]; gcu[1][1] = gzb[bt + 4 + kc]; gcu[1][2] = gnb[bt + 4 + kc];
        }
    }
#undef GRU_STEP
}

__global__ __launch_bounds__(512, 1) void k_recur(
    const uint32_t* __restrict__ gi_ft, const uint32_t* __restrict__ gi_bt,
    const float* __restrict__ Wf_hh, const float* __restrict__ bf_hh,
    const float* __restrict__ Wb_hh, const float* __restrict__ bb_hh,
    const float* __restrict__ h0,
    float* __restrict__ fwd, float* __restrict__ bwd)
{
    if (blockIdx.x == 0) gru_run<0>(gi_ft, Wf_hh, bf_hh, h0, fwd);
    else                 gru_run<1>(gi_bt, Wb_hh, bb_hh, h0, bwd);
}

// ---------------------------------------------------------------------------
// Kernel 3a: logits + softmax, PARALLEL over t (8 blocks x 256 t each).
// W_out staged in LDS (384 float4 > 256 threads -> STRIDED loop, R9 bugfix);
// probs -> workspace (aliases gi_ft, dead after k_recur).
// ---------------------------------------------------------------------------
__global__ __launch_bounds__(256) void k_logits(
    const float* __restrict__ fwd, const float* __restrict__ bwd,
    const float* __restrict__ W_out, const float* __restrict__ b_out,
    float* __restrict__ probs)
{
    __shared__ __align__(16) float4 Wl[NS][64];   // 6KB = 384 float4
    __shared__ float bl[NS];

    const int tid = threadIdx.x;
    for (int i = tid; i < NS * 64; i += 256)      // R9 bug: was if(tid<384)
        Wl[i >> 6][i & 63] = ((const float4*)W_out)[i];
    if (tid < NS) bl[tid] = b_out[tid];
    __syncthreads();

    const int t = blockIdx.x * 256 + tid;
    const float4* f4 = (const float4*)(fwd + (size_t)t * HID);
    const float4* b4 = (const float4*)(bwd + (size_t)t * HID);
    float lg[NS];
#pragma unroll
    for (int s = 0; s < NS; ++s) lg[s] = bl[s];
#pragma unroll 4
    for (int k4 = 0; k4 < 32; ++k4) {
        const float4 fv = f4[k4];
        const float4 bv = b4[k4];
#pragma unroll
        for (int s = 0; s < NS; ++s) {
            const float4 wf = Wl[s][k4];
            const float4 wb = Wl[s][k4 + 32];
            lg[s] += wf.x * fv.x + wf.y * fv.y + wf.z * fv.z + wf.w * fv.w
                   + wb.x * bv.x + wb.y * bv.y + wb.z * bv.z + wb.w * bv.w;
        }
    }
    float m = lg[0];
#pragma unroll
    for (int s = 1; s < NS; ++s) m = fmaxf(m, lg[s]);
    float sum = 0.f;
#pragma unroll
    for (int s = 0; s < NS; ++s) { lg[s] = __expf(lg[s] - m); sum += lg[s]; }
    const float inv = 1.f / sum;
    float* po = probs + (size_t)t * NS;
    *(float2*)(po)     = float2{lg[0] * inv, lg[1] * inv};
    *(float2*)(po + 2) = float2{lg[2] * inv, lg[3] * inv};
    *(float2*)(po + 4) = float2{lg[4] * inv, lg[5] * inv};
}

// ---------------------------------------------------------------------------
// Kernel 3b: PARALLEL Viterbi via (max,+) segmented scan + backtrack.
//  B1: 192 thr (chunk c, row i): per-chunk 6x6 (max,+) products P_c
//  B2: 1 thr: splice 32 chunk-start trellis vectors
//  B3: 32 thr: per-chunk re-walk with full 6-vector in registers (no
//      cross-lane ops), packed 3-bit backpointers; lane 31 emits score.
//  C1-C3: chunked backtrack (reads packed bps).
// ---------------------------------------------------------------------------
__global__ __launch_bounds__(G3) void k_viterbi(
    const float* __restrict__ probs, const float* __restrict__ trans,
    float* __restrict__ out)
{
    __shared__ float p_lds[SEQ * NS];                 // 49152 B
    __shared__ uint32_t bp32[SEQ - 1];                // 8188 B (packed 3b x 6)
    __shared__ float Pmat[32][NS][NS];                // 4608 B
    __shared__ float vstart[32][NS];                  // 768 B
    __shared__ unsigned char cmap[32 * NS];
    __shared__ int bstate[32];
    __shared__ int s_last;

    const int tid = threadIdx.x;

    // ---- load probs into LDS (float4) ----
    {
        const float4* src = (const float4*)probs;
        float4* dst = (float4*)p_lds;
#pragma unroll
        for (int r = 0; r < 8; ++r) dst[tid + r * G3] = src[tid + r * G3];
    }
    __syncthreads();

    // ---- B1: per-chunk (max,+) products ----
    if (tid < 32 * NS) {
        const int c = tid / NS, i = tid % NS;
        float tc[NS][NS];
#pragma unroll
        for (int k = 0; k < NS; ++k)
#pragma unroll
            for (int j = 0; j < NS; ++j) tc[k][j] = trans[k * NS + j];
        float R[NS];
#pragma unroll
        for (int j = 0; j < NS; ++j) R[j] = (j == i) ? 0.f : -3.0e38f;
        const int lo = 64 * c;
        const int hi = (c == 31) ? (SEQ - 1) : 64 * (c + 1);
        for (int tau = lo + 1; tau <= hi; ++tau) {
            const float2 p01 = *(const float2*)&p_lds[tau * NS];
            const float2 p23 = *(const float2*)&p_lds[tau * NS + 2];
            const float2 p45 = *(const float2*)&p_lds[tau * NS + 4];
            const float pj[NS] = {p01.x, p01.y, p23.x, p23.y, p45.x, p45.y};
            float Rn[NS];
#pragma unroll
            for (int j = 0; j < NS; ++j) {
                float mx = R[0] + tc[0][j];
                mx = fmaxf(mx, R[1] + tc[1][j]);
                mx = fmaxf(mx, R[2] + tc[2][j]);
                mx = fmaxf(mx, R[3] + tc[3][j]);
                mx = fmaxf(mx, R[4] + tc[4][j]);
                mx = fmaxf(mx, R[5] + tc[5][j]);
                Rn[j] = mx + pj[j];
            }
#pragma unroll
            for (int j = 0; j < NS; ++j) R[j] = Rn[j];
        }
#pragma unroll
        for (int j = 0; j < NS; ++j) Pmat[c][i][j] = R[j];
    }
    __syncthreads();

    // ---- B2: serial splice of chunk-start trellis vectors ----
    if (tid == 0) {
        float v[NS];
#pragma unroll
        for (int j = 0; j < NS; ++j) { v[j] = p_lds[j]; vstart[0][j] = v[j]; }
        for (int c = 0; c < 31; ++c) {
            float vn[NS];
#pragma unroll
            for (int j = 0; j < NS; ++j) {
                float mx = v[0] + Pmat[c][0][j];
                mx = fmaxf(mx, v[1] + Pmat[c][1][j]);
                mx = fmaxf(mx, v[2] + Pmat[c][2][j]);
                mx = fmaxf(mx, v[3] + Pmat[c][3][j]);
                mx = fmaxf(mx, v[4] + Pmat[c][4][j]);
                mx = fmaxf(mx, v[5] + Pmat[c][5][j]);
                vn[j] = mx;
            }
#pragma unroll
            for (int j = 0; j < NS; ++j) { v[j] = vn[j]; vstart[c + 1][j] = vn[j]; }
        }
    }
    __syncthreads();

    // ---- B3: per-chunk re-walk (lane c), packed backpointers ----
    if (tid < 32) {
        const int c = tid;
        float tc[NS][NS];
#pragma unroll
        for (int k = 0; k < NS; ++k)
#pragma unroll
            for (int j = 0; j < NS; ++j) tc[k][j] = trans[k * NS + j];
        float v[NS];
#pragma unroll
        for (int j = 0; j < NS; ++j) v[j] = vstart[c][j];
        const int lo = 64 * c;
        const int hi = (c == 31) ? (SEQ - 1) : 64 * (c + 1);
        for (int tau = lo + 1; tau <= hi; ++tau) {
            const float2 p01 = *(const float2*)&p_lds[tau * NS];
            const float2 p23 = *(const float2*)&p_lds[tau * NS + 2];
            const float2 p45 = *(const float2*)&p_lds[tau * NS + 4];
            const float pj[NS] = {p01.x, p01.y, p23.x, p23.y, p45.x, p45.y};
            uint32_t bpw = 0;
            float vn[NS];
#pragma unroll
            for (int j = 0; j < NS; ++j) {
                const float c0 = v[0] + tc[0][j];
                const float c1 = v[1] + tc[1][j];
                const float c2 = v[2] + tc[2][j];
                const float c3 = v[3] + tc[3][j];
                const float c4 = v[4] + tc[4][j];
                const float c5 = v[5] + tc[5][j];
                const float best = fmaxf(fmaxf(fmaxf(c0, c1), c2),
                                         fmaxf(fmaxf(c3, c4), c5));
                int bi = 5;                       // first-max (== jnp.argmax)
                bi = (c4 == best) ? 4 : bi;
                bi = (c3 == best) ? 3 : bi;
                bi = (c2 == best) ? 2 : bi;
                bi = (c1 == best) ? 1 : bi;
                bi = (c0 == best) ? 0 : bi;
                bpw |= ((uint32_t)bi) << (3 * j);
                vn[j] = pj[j] + best;
            }
            bp32[tau - 1] = bpw;
#pragma unroll
            for (int j = 0; j < NS; ++j) v[j] = vn[j];
        }
        if (c == 31) {
            const float best = fmaxf(fmaxf(fmaxf(v[0], v[1]), v[2]),
                                     fmaxf(fmaxf(v[3], v[4]), v[5]));
            int bi = 5;
            bi = (v[4] == best) ? 4 : bi;
            bi = (v[3] == best) ? 3 : bi;
            bi = (v[2] == best) ? 2 : bi;
            bi = (v[1] == best) ? 1 : bi;
            bi = (v[0] == best) ? 0 : bi;
            out[0] = best; s_last = bi;
        }
    }
    __syncthreads();

    // ---- C1: per-chunk backpointer composition (192 walkers) ----
    if (tid < 32 * NS) {
        const int c = tid / NS, s0 = tid % NS;
        const int hi = (c == 31) ? (SEQ - 1) : 64 * (c + 1);
        const int lo = 64 * c;
        int s = s0;
        for (int tau = hi; tau > lo; --tau)
            s = (bp32[tau - 1] >> (3 * s)) & 7;
        cmap[c * NS + s0] = (unsigned char)s;
    }
    __syncthreads();

    // ---- C2: serial splice over 32 chunk boundaries ----
    if (tid == 0) {
        int s = s_last;
        for (int c = 31; c >= 0; --c) {
            s = cmap[c * NS + s];
            bstate[c] = s;
        }
    }
    __syncthreads();

    // ---- C3: parallel emit (32 chunks re-walk) ----
    if (tid < 32) {
        const int c = tid;
        const int hi = (c == 31) ? (SEQ - 1) : 64 * (c + 1);
        const int lo = 64 * c;
        int s = (c == 31) ? s_last : bstate[c + 1];
        for (int tau = hi; tau > lo; --tau) {
            out[1 + tau] = (float)s;
            s = (bp32[tau - 1] >> (3 * s)) & 7;
        }
        if (c == 0) out[1] = (float)s;   // time 0
    }
}

// ---------------------------------------------------------------------------
extern "C" void kernel_launch(void* const* d_in, const int* in_sizes, int n_in,
                              void* d_out, int out_size, void* d_ws, size_t ws_size,
                              hipStream_t stream)
{
    (void)in_sizes; (void)n_in; (void)out_size; (void)ws_size;

    const int*   sent  = (const int*)  d_in[0];
    const float* emb   = (const float*)d_in[1];
    const float* h0    = (const float*)d_in[2];
    const float* Wf_ih = (const float*)d_in[3];
    const float* Wf_hh = (const float*)d_in[4];
    const float* bf_ih = (const float*)d_in[5];
    const float* bf_hh = (const float*)d_in[6];
    const float* Wb_ih = (const float*)d_in[7];
    const float* Wb_hh = (const float*)d_in[8];
    const float* bb_ih = (const float*)d_in[9];
    const float* bb_hh = (const float*)d_in[10];
    const float* W_out = (const float*)d_in[11];
    const float* b_out = (const float*)d_in[12];
    const float* trans = (const float*)d_in[13];
    float* out = (float*)d_out;

    // workspace layout (floats): gi_ft | gi_bt | fwd | bwd.
    // probs (SEQ*NS floats) ALIASES gi_ft — dead after k_recur, which
    // strictly precedes k_logits on the stream (keeps footprint == R8).
    float*    ws    = (float*)d_ws;
    uint32_t* gi_ft = (uint32_t*)ws;
    uint32_t* gi_bt = gi_ft + (size_t)SEQ * 192;
    float*    fwdb  = ws + (size_t)2 * SEQ * G3;
    float*    bwdb  = fwdb + (size_t)SEQ * HID;
    float*    probs = ws;                     // alias of gi_ft region

    k_input_proj<<<SEQ / 4, G3, 0, stream>>>(sent, emb, Wf_ih, bf_ih, Wb_ih, bb_ih, gi_ft, gi_bt);
    k_recur<<<2, 512, 0, stream>>>(gi_ft, gi_bt, Wf_hh, bf_hh, Wb_hh, bb_hh, h0, fwdb, bwdb);
    k_logits<<<SEQ / 256, 256, 0, stream>>>(fwdb, bwdb, W_out, b_out, probs);
    k_viterbi<<<1, G3, 0, stream>>>(probs, trans, out);
}

// Round 11
// 1057.442 us; speedup vs baseline: 1.7030x; 1.0984x over previous
//
#include <hip/hip_runtime.h>
#include <math.h>
#include <stdint.h>

// Problem constants (from reference setup_inputs)
constexpr int SEQ   = 2048;  // T
constexpr int BATCH = 64;    // B
constexpr int EMB   = 100;   // E
constexpr int HID   = 128;   // H
constexpr int G3    = 384;   // 3*H
constexpr int NS    = 6;     // S (CRF states)
constexpr int BSEL  = 63;    // only batch row 63 affects the output

#define KEEPI(v) asm volatile("" : "+v"(v))

typedef _Float16 f16x2 __attribute__((ext_vector_type(2)));

#if defined(__has_builtin)
#if __has_builtin(__builtin_amdgcn_fdot2)
#define HAVE_FDOT2 1
#endif
#endif

// Packed f16 dot with fp32 accumulate. If the builtin is missing on this
// toolchain, emit the instruction directly — R6-R10's VALUBusy (~1060
// cyc/SIMD/step vs ~400 expected) indicates the cvt+fma fallback was in
// use, i.e. 4 VALU ops per pair instead of 1.
__device__ __forceinline__ float dot2(uint32_t w, uint32_t h, float acc) {
#ifdef HAVE_FDOT2
    return __builtin_amdgcn_fdot2(__builtin_bit_cast(f16x2, w),
                                  __builtin_bit_cast(f16x2, h), acc, false);
#else
    asm("v_dot2_f32_f16 %0, %1, %2, %0" : "+v"(acc) : "v"(w), "v"(h));
    return acc;
#endif
}

__device__ __forceinline__ uint32_t pack_f16(float a, float b) {
    f16x2 p; p.x = (_Float16)a; p.y = (_Float16)b;
    return __builtin_bit_cast(uint32_t, p);
}

__device__ __forceinline__ float half_sel(uint32_t p, int hi) {
    const f16x2 v = __builtin_bit_cast(f16x2, p);
    return hi ? (float)v.y : (float)v.x;
}

template <int CTRL>
__device__ __forceinline__ float dpp_add(float x) {
    int v = __builtin_amdgcn_update_dpp(0, __float_as_int(x), CTRL, 0xF, 0xF, true);
    return x + __int_as_float(v);
}
template <int CTRL>
__device__ __forceinline__ uint32_t dpp_bcast(uint32_t x) {
    return (uint32_t)__builtin_amdgcn_update_dpp(0, (int)x, CTRL, 0xF, 0xF, true);
}

// ---------------------------------------------------------------------------
// Kernel 1: embedding lookup + input projection for batch row 63 only.
// Emits gi TRANSPOSED as packed f16 unit-pairs (unchanged from R8).
// ---------------------------------------------------------------------------
__global__ __launch_bounds__(G3) void k_input_proj(
    const int* __restrict__ sent, const float* __restrict__ emb,
    const float* __restrict__ Wf_ih, const float* __restrict__ bf_ih,
    const float* __restrict__ Wb_ih, const float* __restrict__ bb_ih,
    uint32_t* __restrict__ gi_ft, uint32_t* __restrict__ gi_bt)
{
    const int tb = blockIdx.x * 4;
    const int j  = threadIdx.x;           // 0..383 = weight row (g*128 + u)
    __shared__ __align__(16) float x_s[4][EMB];

    int toks[4];
#pragma unroll
    for (int tt = 0; tt < 4; ++tt) toks[tt] = sent[BSEL * SEQ + tb + tt];
    if (j < EMB) {
#pragma unroll
        for (int tt = 0; tt < 4; ++tt)
            x_s[tt][j] = emb[(size_t)toks[tt] * EMB + j];
    }
    __syncthreads();

    float4 wf4[25], wb4[25];
    const float4* wfp = (const float4*)(Wf_ih + (size_t)j * EMB);
    const float4* wbp = (const float4*)(Wb_ih + (size_t)j * EMB);
#pragma unroll
    for (int m = 0; m < 25; ++m) { wf4[m] = wfp[m]; wb4[m] = wbp[m]; }
    const float bf = bf_ih[j], bb = bb_ih[j];

    const int g  = j >> 7;
    const int u  = j & 127;
    const int u2 = u >> 1;
    const size_t orow = ((size_t)(g * 64 + u2)) * SEQ;

#pragma unroll
    for (int tt = 0; tt < 4; ++tt) {
        const float4* xs = (const float4*)(x_s[tt]);
        float af = 0.f, ab = 0.f;
#pragma unroll
        for (int m = 0; m < 25; ++m) {
            const float4 xv = xs[m];
            af = fmaf(wf4[m].x, xv.x, af); af = fmaf(wf4[m].y, xv.y, af);
            af = fmaf(wf4[m].z, xv.z, af); af = fmaf(wf4[m].w, xv.w, af);
            ab = fmaf(wb4[m].x, xv.x, ab); ab = fmaf(wb4[m].y, xv.y, ab);
            ab = fmaf(wb4[m].z, xv.z, ab); ab = fmaf(wb4[m].w, xv.w, ab);
        }
        const float vf = af + bf;
        const float vb = ab + bb;
        const float vf_n = __shfl_xor(vf, 1);
        const float vb_n = __shfl_xor(vb, 1);
        if ((u & 1) == 0) {
            gi_ft[orow + tb + tt] = pack_f16(vf, vf_n);
            gi_bt[orow + tb + tt] = pack_f16(vb, vb_n);
        }
    }
}

// ---------------------------------------------------------------------------
// Kernel 2: GRU recurrence, 256 threads/block (one block per direction).
// Thread = (unit u = tid>>1, half = tid&1 -> 64-col slice). 1 wave/SIMD
// (amdgpu_waves_per_eu(1,1) -> 512-VGPR budget so the 96 packed weights
// live in arch VGPRs). Per step: 8 broadcast ds_read_b128, 96 dot2,
// ONE dpp pair-add, gates on both lanes (redundant), half==0 writes h.
// gi loaded once per 8-step window (quad = unit-pair u2; lane kq=tid&3
// holds t-slots {2kq,2kq+1}); outputs buffered, stored once per window
// -> per-step barrier drains nothing (R8-proven).
// ---------------------------------------------------------------------------
template <int DIR>
__device__ void gru_run(const uint32_t* __restrict__ git,
                        const float* __restrict__ Whh,
                        const float* __restrict__ bhh,
                        const float* __restrict__ h0,
                        float* __restrict__ outs)
{
    const int tid  = threadIdx.x;         // 0..255
    const int u    = tid >> 1;            // unit 0..127
    const int half = tid & 1;             // 64-col slice
    const int u2   = u >> 1;              // == tid>>2 == quad index
    const int kq   = tid & 3;             // lane-in-quad
    const int halfu = u & 1;              // which half of the u2 pack

    // --- weights: rows {u, 128+u, 256+u}, cols [64*half, 64*half+64), f16
    uint32_t Wp0[32], Wp1[32], Wp2[32];
    {
        const float* r0 = Whh + (size_t)u * HID + 64 * half;
        const float* r1 = Whh + (size_t)(HID + u) * HID + 64 * half;
        const float* r2 = Whh + (size_t)(2 * HID + u) * HID + 64 * half;
#pragma unroll
        for (int m4 = 0; m4 < 16; ++m4) {
            const float4 a = ((const float4*)r0)[m4];
            const float4 b = ((const float4*)r1)[m4];
            const float4 c = ((const float4*)r2)[m4];
            Wp0[2 * m4] = pack_f16(a.x, a.y); Wp0[2 * m4 + 1] = pack_f16(a.z, a.w);
            Wp1[2 * m4] = pack_f16(b.x, b.y); Wp1[2 * m4 + 1] = pack_f16(b.z, b.w);
            Wp2[2 * m4] = pack_f16(c.x, c.y); Wp2[2 * m4 + 1] = pack_f16(c.z, c.w);
        }
#pragma unroll
        for (int m = 0; m < 32; ++m) { KEEPI(Wp0[m]); KEEPI(Wp1[m]); KEEPI(Wp2[m]); }
    }

    const float b_r = bhh[u];
    const float b_z = bhh[HID + u];
    const float b_n = bhh[2 * HID + u];

    float h_u = h0[(size_t)DIR * BATCH * HID + BSEL * HID + u];

    const uint32_t* grb = git + (size_t)(0 * 64 + u2) * SEQ;
    const uint32_t* gzb = git + (size_t)(1 * 64 + u2) * SEQ;
    const uint32_t* gnb = git + (size_t)(2 * 64 + u2) * SEQ;

    __shared__ __align__(16) uint32_t h_lds[2][HID / 2];
    if (tid < HID / 2) {
        const float2 hh = *(const float2*)(h0 + (size_t)DIR * BATCH * HID + BSEL * HID + 2 * tid);
        h_lds[0][tid] = pack_f16(hh.x, hh.y);
    }

    // window-0 gi: lane kq holds in-window t-slots 2kq and 2kq+1
    uint32_t gcu[2][3];
    {
        const int bt = DIR ? (SEQ - 8) : 0;
        gcu[0][0] = grb[bt + 2 * kq];     gcu[0][1] = gzb[bt + 2 * kq];     gcu[0][2] = gnb[bt + 2 * kq];
        gcu[1][0] = grb[bt + 2 * kq + 1]; gcu[1][1] = gzb[bt + 2 * kq + 1]; gcu[1][2] = gnb[bt + 2 * kq + 1];
    }
    __syncthreads();   // drains prologue loads once

    float hs0 = 0, hs1 = 0, hs2 = 0, hs3 = 0, hs4 = 0, hs5 = 0, hs6 = 0, hs7 = 0;

#define GRU_STEP(I, KIDX) do {                                                 \
    const uint4* hb4 = (const uint4*)(h_lds[(I) & 1]) + half * 8;              \
    uint32_t hw[32];                                                           \
    _Pragma("unroll")                                                          \
    for (int m = 0; m < 8; ++m) {                                              \
        const uint4 q = hb4[m];                                                \
        hw[4 * m + 0] = q.x; hw[4 * m + 1] = q.y;                              \
        hw[4 * m + 2] = q.z; hw[4 * m + 3] = q.w;                              \
    }                                                                          \
    float ar = 0.f, az = 0.f, an = 0.f;                                        \
    _Pragma("unroll")                                                          \
    for (int k = 0; k < 32; ++k) {                                             \
        ar = dot2(Wp0[k], hw[k], ar);                                          \
        az = dot2(Wp1[k], hw[k], az);                                          \
        an = dot2(Wp2[k], hw[k], an);                                          \
    }                                                                          \
    ar = dpp_add<0xB1>(ar);                                                    \
    az = dpp_add<0xB1>(az);                                                    \
    an = dpp_add<0xB1>(an);                                                    \
    const uint32_t gur = dpp_bcast<((KIDX) >> 1) * 0x55>(gcu[(KIDX) & 1][0]);  \
    const uint32_t guz = dpp_bcast<((KIDX) >> 1) * 0x55>(gcu[(KIDX) & 1][1]);  \
    const uint32_t gun = dpp_bcast<((KIDX) >> 1) * 0x55>(gcu[(KIDX) & 1][2]);  \
    const float gr = half_sel(gur, halfu) + b_r;                               \
    const float gz = half_sel(guz, halfu) + b_z;                               \
    const float gn = half_sel(gun, halfu);                                     \
    const float rg = __builtin_amdgcn_rcpf(1.f + __expf(-(gr + ar)));          \
    const float zg = __builtin_amdgcn_rcpf(1.f + __expf(-(gz + az)));          \
    float ttv = gn + rg * (an + b_n);                                          \
    ttv = fminf(fmaxf(ttv, -15.f), 15.f);                                      \
    const float e = __expf(-2.f * ttv);                                        \
    const float ng = fmaf(2.f, __builtin_amdgcn_rcpf(1.f + e), -1.f);          \
    h_u = (1.f - zg) * ng + zg * h_u;                                          \
    if (half == 0) {                                                           \
        hs##I = h_u;                                                           \
        ((_Float16*)(h_lds[((I) & 1) ^ 1]))[u] = (_Float16)h_u;                \
    }                                                                          \
    __syncthreads();                                                           \
} while (0)

    constexpr int NW = SEQ / 8;
    for (int w = 0; w < NW; ++w) {
        GRU_STEP(0, (DIR ? 7 : 0));
        GRU_STEP(1, (DIR ? 6 : 1));
        GRU_STEP(2, (DIR ? 5 : 2));
        GRU_STEP(3, (DIR ? 4 : 3));
        GRU_STEP(4, (DIR ? 3 : 4));
        GRU_STEP(5, (DIR ? 2 : 5));
        GRU_STEP(6, (DIR ? 1 : 6));
        GRU_STEP(7, (DIR ? 0 : 7));

        // window-end writeback (half==0 lanes: this unit's 8 timesteps)
        if (half == 0) {
            const int t0 = DIR ? (SEQ - 1 - 8 * w) : 8 * w;
            const int ti = DIR ? -1 : 1;
            outs[(size_t)(t0 + 0 * ti) * HID + u] = hs0;
            outs[(size_t)(t0 + 1 * ti) * HID + u] = hs1;
            outs[(size_t)(t0 + 2 * ti) * HID + u] = hs2;
            outs[(size_t)(t0 + 3 * ti) * HID + u] = hs3;
            outs[(size_t)(t0 + 4 * ti) * HID + u] = hs4;
            outs[(size_t)(t0 + 5 * ti) * HID + u] = hs5;
            outs[(size_t)(t0 + 6 * ti) * HID + u] = hs6;
            outs[(size_t)(t0 + 7 * ti) * HID + u] = hs7;
        }
        // next-window gi (drained at next window's first barrier)
        if (w + 1 < NW) {
            const int bt = DIR ? (SEQ - 8 - 8 * (w + 1)) : (8 * (w + 1));
            gcu[0][0] = grb[bt + 2 * kq];     gcu[0][1] = gzb[bt + 2 * kq];     gcu[0][2] = gnb[bt + 2 * kq];
            gcu[1][0] = grb[bt + 2 * kq + 1]; gcu[1][1] = gzb[bt + 2 * kq + 1]; gcu[1][2] = gnb[bt + 2 * kq + 1];
        }
    }
#undef GRU_STEP
}

__global__ __launch_bounds__(256)
__attribute__((amdgpu_waves_per_eu(1, 1)))
void k_recur(
    const uint32_t* __restrict__ gi_ft, const uint32_t* __restrict__ gi_bt,
    const float* __restrict__ Wf_hh, const float* __restrict__ bf_hh,
    const float* __restrict__ Wb_hh, const float* __restrict__ bb_hh,
    const float* __restrict__ h0,
    float* __restrict__ fwd, float* __restrict__ bwd)
{
    if (blockIdx.x == 0) gru_run<0>(gi_ft, Wf_hh, bf_hh, h0, fwd);
    else                 gru_run<1>(gi_bt, Wb_hh, bb_hh, h0, bwd);
}

// ---------------------------------------------------------------------------
// Kernel 3a: logits + softmax, PARALLEL over t (8 blocks x 256 t each).
// (R10-verified, unchanged)
// ---------------------------------------------------------------------------
__global__ __launch_bounds__(256) void k_logits(
    const float* __restrict__ fwd, const float* __restrict__ bwd,
    const float* __restrict__ W_out, const float* __restrict__ b_out,
    float* __restrict__ probs)
{
    __shared__ __align__(16) float4 Wl[NS][64];   // 6KB = 384 float4
    __shared__ float bl[NS];

    const int tid = threadIdx.x;
    for (int i = tid; i < NS * 64; i += 256)
        Wl[i >> 6][i & 63] = ((const float4*)W_out)[i];
    if (tid < NS) bl[tid] = b_out[tid];
    __syncthreads();

    const int t = blockIdx.x * 256 + tid;
    const float4* f4 = (const float4*)(fwd + (size_t)t * HID);
    const float4* b4 = (const float4*)(bwd + (size_t)t * HID);
    float lg[NS];
#pragma unroll
    for (int s = 0; s < NS; ++s) lg[s] = bl[s];
#pragma unroll 4
    for (int k4 = 0; k4 < 32; ++k4) {
        const float4 fv = f4[k4];
        const float4 bv = b4[k4];
#pragma unroll
        for (int s = 0; s < NS; ++s) {
            const float4 wf = Wl[s][k4];
            const float4 wb = Wl[s][k4 + 32];
            lg[s] += wf.x * fv.x + wf.y * fv.y + wf.z * fv.z + wf.w * fv.w
                   + wb.x * bv.x + wb.y * bv.y + wb.z * bv.z + wb.w * bv.w;
        }
    }
    float m = lg[0];
#pragma unroll
    for (int s = 1; s < NS; ++s) m = fmaxf(m, lg[s]);
    float sum = 0.f;
#pragma unroll
    for (int s = 0; s < NS; ++s) { lg[s] = __expf(lg[s] - m); sum += lg[s]; }
    const float inv = 1.f / sum;
    float* po = probs + (size_t)t * NS;
    *(float2*)(po)     = float2{lg[0] * inv, lg[1] * inv};
    *(float2*)(po + 2) = float2{lg[2] * inv, lg[3] * inv};
    *(float2*)(po + 4) = float2{lg[4] * inv, lg[5] * inv};
}

// ---------------------------------------------------------------------------
// Kernel 3b: PARALLEL Viterbi via (max,+) segmented scan + backtrack.
// (R10-verified, unchanged)
// ---------------------------------------------------------------------------
__global__ __launch_bounds__(G3) void k_viterbi(
    const float* __restrict__ probs, const float* __restrict__ trans,
    float* __restrict__ out)
{
    __shared__ float p_lds[SEQ * NS];
    __shared__ uint32_t bp32[SEQ - 1];
    __shared__ float Pmat[32][NS][NS];
    __shared__ float vstart[32][NS];
    __shared__ unsigned char cmap[32 * NS];
    __shared__ int bstate[32];
    __shared__ int s_last;

    const int tid = threadIdx.x;

    {
        const float4* src = (const float4*)probs;
        float4* dst = (float4*)p_lds;
#pragma unroll
        for (int r = 0; r < 8; ++r) dst[tid + r * G3] = src[tid + r * G3];
    }
    __syncthreads();

    if (tid < 32 * NS) {
        const int c = tid / NS, i = tid % NS;
        float tc[NS][NS];
#pragma unroll
        for (int k = 0; k < NS; ++k)
#pragma unroll
            for (int j = 0; j < NS; ++j) tc[k][j] = trans[k * NS + j];
        float R[NS];
#pragma unroll
        for (int j = 0; j < NS; ++j) R[j] = (j == i) ? 0.f : -3.0e38f;
        const int lo = 64 * c;
        const int hi = (c == 31) ? (SEQ - 1) : 64 * (c + 1);
        for (int tau = lo + 1; tau <= hi; ++tau) {
            const float2 p01 = *(const float2*)&p_lds[tau * NS];
            const float2 p23 = *(const float2*)&p_lds[tau * NS + 2];
            const float2 p45 = *(const float2*)&p_lds[tau * NS + 4];
            const float pj[NS] = {p01.x, p01.y, p23.x, p23.y, p45.x, p45.y};
            float Rn[NS];
#pragma unroll
            for (int j = 0; j < NS; ++j) {
                float mx = R[0] + tc[0][j];
                mx = fmaxf(mx, R[1] + tc[1][j]);
                mx = fmaxf(mx, R[2] + tc[2][j]);
                mx = fmaxf(mx, R[3] + tc[3][j]);
                mx = fmaxf(mx, R[4] + tc[4][j]);
                mx = fmaxf(mx, R[5] + tc[5][j]);
                Rn[j] = mx + pj[j];
            }
#pragma unroll
            for (int j = 0; j < NS; ++j) R[j] = Rn[j];
        }
#pragma unroll
        for (int j = 0; j < NS; ++j) Pmat[c][i][j] = R[j];
    }
    __syncthreads();

    if (tid == 0) {
        float v[NS];
#pragma unroll
        for (int j = 0; j < NS; ++j) { v[j] = p_lds[j]; vstart[0][j] = v[j]; }
        for (int c = 0; c < 31; ++c) {
            float vn[NS];
#pragma unroll
            for (int j = 0; j < NS; ++j) {
                float mx = v[0] + Pmat[c][0][j];
                mx = fmaxf(mx, v[1] + Pmat[c][1][j]);
                mx = fmaxf(mx, v[2] + Pmat[c][2][j]);
                mx = fmaxf(mx, v[3] + Pmat[c][3][j]);
                mx = fmaxf(mx, v[4] + Pmat[c][4][j]);
                mx = fmaxf(mx, v[5] + Pmat[c][5][j]);
                vn[j] = mx;
            }
#pragma unroll
            for (int j = 0; j < NS; ++j) { v[j] = vn[j]; vstart[c + 1][j] = vn[j]; }
        }
    }
    __syncthreads();

    if (tid < 32) {
        const int c = tid;
        float tc[NS][NS];
#pragma unroll
        for (int k = 0; k < NS; ++k)
#pragma unroll
            for (int j = 0; j < NS; ++j) tc[k][j] = trans[k * NS + j];
        float v[NS];
#pragma unroll
        for (int j = 0; j < NS; ++j) v[j] = vstart[c][j];
        const int lo = 64 * c;
        const int hi = (c == 31) ? (SEQ - 1) : 64 * (c + 1);
        for (int tau = lo + 1; tau <= hi; ++tau) {
            const float2 p01 = *(const float2*)&p_lds[tau * NS];
            const float2 p23 = *(const float2*)&p_lds[tau * NS + 2];
            const float2 p45 = *(const float2*)&p_lds[tau * NS + 4];
            const float pj[NS] = {p01.x, p01.y, p23.x, p23.y, p45.x, p45.y};
            uint32_t bpw = 0;
            float vn[NS];
#pragma unroll
            for (int j = 0; j < NS; ++j) {
                const float c0 = v[0] + tc[0][j];
                const float c1 = v[1] + tc[1][j];
                const float c2 = v[2] + tc[2][j];
                const float c3 = v[3] + tc[3][j];
                const float c4 = v[4] + tc[4][j];
                const float c5 = v[5] + tc[5][j];
                const float best = fmaxf(fmaxf(fmaxf(c0, c1), c2),
                                         fmaxf(fmaxf(c3, c4), c5));
                int bi = 5;
                bi = (c4 == best) ? 4 : bi;
                bi = (c3 == best) ? 3 : bi;
                bi = (c2 == best) ? 2 : bi;
                bi = (c1 == best) ? 1 : bi;
                bi = (c0 == best) ? 0 : bi;
                bpw |= ((uint32_t)bi) << (3 * j);
                vn[j] = pj[j] + best;
            }
            bp32[tau - 1] = bpw;
#pragma unroll
            for (int j = 0; j < NS; ++j) v[j] = vn[j];
        }
        if (c == 31) {
            const float best = fmaxf(fmaxf(fmaxf(v[0], v[1]), v[2]),
                                     fmaxf(fmaxf(v[3], v[4]), v[5]));
            int bi = 5;
            bi = (v[4] == best) ? 4 : bi;
            bi = (v[3] == best) ? 3 : bi;
            bi = (v[2] == best) ? 2 : bi;
            bi = (v[1] == best) ? 1 : bi;
            bi = (v[0] == best) ? 0 : bi;
            out[0] = best; s_last = bi;
        }
    }
    __syncthreads();

    if (tid < 32 * NS) {
        const int c = tid / NS, s0 = tid % NS;
        const int hi = (c == 31) ? (SEQ - 1) : 64 * (c + 1);
        const int lo = 64 * c;
        int s = s0;
        for (int tau = hi; tau > lo; --tau)
            s = (bp32[tau - 1] >> (3 * s)) & 7;
        cmap[c * NS + s0] = (unsigned char)s;
    }
    __syncthreads();

    if (tid == 0) {
        int s = s_last;
        for (int c = 31; c >= 0; --c) {
            s = cmap[c * NS + s];
            bstate[c] = s;
        }
    }
    __syncthreads();

    if (tid < 32) {
        const int c = tid;
        const int hi = (c == 31) ? (SEQ - 1) : 64 * (c + 1);
        const int lo = 64 * c;
        int s = (c == 31) ? s_last : bstate[c + 1];
        for (int tau = hi; tau > lo; --tau) {
            out[1 + tau] = (float)s;
            s = (bp32[tau - 1] >> (3 * s)) & 7;
        }
        if (c == 0) out[1] = (float)s;   // time 0
    }
}

// ---------------------------------------------------------------------------
extern "C" void kernel_launch(void* const* d_in, const int* in_sizes, int n_in,
                              void* d_out, int out_size, void* d_ws, size_t ws_size,
                              hipStream_t stream)
{
    (void)in_sizes; (void)n_in; (void)out_size; (void)ws_size;

    const int*   sent  = (const int*)  d_in[0];
    const float* emb   = (const float*)d_in[1];
    const float* h0    = (const float*)d_in[2];
    const float* Wf_ih = (const float*)d_in[3];
    const float* Wf_hh = (const float*)d_in[4];
    const float* bf_ih = (const float*)d_in[5];
    const float* bf_hh = (const float*)d_in[6];
    const float* Wb_ih = (const float*)d_in[7];
    const float* Wb_hh = (const float*)d_in[8];
    const float* bb_ih = (const float*)d_in[9];
    const float* bb_hh = (const float*)d_in[10];
    const float* W_out = (const float*)d_in[11];
    const float* b_out = (const float*)d_in[12];
    const float* trans = (const float*)d_in[13];
    float* out = (float*)d_out;

    // workspace layout (floats): gi_ft | gi_bt | fwd | bwd.
    // probs aliases gi_ft (dead after k_recur).
    float*    ws    = (float*)d_ws;
    uint32_t* gi_ft = (uint32_t*)ws;
    uint32_t* gi_bt = gi_ft + (size_t)SEQ * 192;
    float*    fwdb  = ws + (size_t)2 * SEQ * G3;
    float*    bwdb  = fwdb + (size_t)SEQ * HID;
    float*    probs = ws;                     // alias of gi_ft region

    k_input_proj<<<SEQ / 4, G3, 0, stream>>>(sent, emb, Wf_ih, bf_ih, Wb_ih, bb_ih, gi_ft, gi_bt);
    k_recur<<<2, 256, 0, stream>>>(gi_ft, gi_bt, Wf_hh, bf_hh, Wb_hh, bb_hh, h0, fwdb, bwdb);
    k_logits<<<SEQ / 256, 256, 0, stream>>>(fwdb, bwdb, W_out, b_out, probs);
    k_viterbi<<<1, G3, 0, stream>>>(probs, trans, out);
}

// Round 12
// 996.364 us; speedup vs baseline: 1.8074x; 1.0613x over previous
//
#include <hip/hip_runtime.h>
#include <math.h>
#include <stdint.h>

// Problem constants (from reference setup_inputs)
constexpr int SEQ   = 2048;  // T
constexpr int BATCH = 64;    // B
constexpr int EMB   = 100;   // E
constexpr int HID   = 128;   // H
constexpr int G3    = 384;   // 3*H
constexpr int NS    = 6;     // S (CRF states)
constexpr int BSEL  = 63;    // only batch row 63 affects the output

#define KEEPI(v) asm volatile("" : "+v"(v))

typedef _Float16 f16x2 __attribute__((ext_vector_type(2)));

#if defined(__has_builtin)
#if __has_builtin(__builtin_amdgcn_fdot2)
#define HAVE_FDOT2 1
#endif
#endif

__device__ __forceinline__ float dot2(uint32_t w, uint32_t h, float acc) {
#ifdef HAVE_FDOT2
    return __builtin_amdgcn_fdot2(__builtin_bit_cast(f16x2, w),
                                  __builtin_bit_cast(f16x2, h), acc, false);
#else
    asm("v_dot2_f32_f16 %0, %1, %2, %0" : "+v"(acc) : "v"(w), "v"(h));
    return acc;
#endif
}

__device__ __forceinline__ uint32_t pack_f16(float a, float b) {
    f16x2 p; p.x = (_Float16)a; p.y = (_Float16)b;
    return __builtin_bit_cast(uint32_t, p);
}

__device__ __forceinline__ float half_sel(uint32_t p, int hi) {
    const f16x2 v = __builtin_bit_cast(f16x2, p);
    return hi ? (float)v.y : (float)v.x;
}

template <int CTRL>
__device__ __forceinline__ float dpp_add(float x) {
    int v = __builtin_amdgcn_update_dpp(0, __float_as_int(x), CTRL, 0xF, 0xF, true);
    return x + __int_as_float(v);
}
template <int CTRL>
__device__ __forceinline__ uint32_t dpp_bcast(uint32_t x) {
    return (uint32_t)__builtin_amdgcn_update_dpp(0, (int)x, CTRL, 0xF, 0xF, true);
}

// ---------------------------------------------------------------------------
// Kernel 1: embedding lookup + input projection for batch row 63 only.
// 16 timesteps per block (4x fewer weight re-reads than R11). Emits gi
// TRANSPOSED as packed f16 unit-pairs (R8-proven layout).
// ---------------------------------------------------------------------------
__global__ __launch_bounds__(G3) void k_input_proj(
    const int* __restrict__ sent, const float* __restrict__ emb,
    const float* __restrict__ Wf_ih, const float* __restrict__ bf_ih,
    const float* __restrict__ Wb_ih, const float* __restrict__ bb_ih,
    uint32_t* __restrict__ gi_ft, uint32_t* __restrict__ gi_bt)
{
    const int tb = blockIdx.x * 16;
    const int j  = threadIdx.x;           // 0..383 = weight row (g*128 + u)
    __shared__ __align__(16) float x_s[16][EMB];

    if (j < EMB) {
        for (int tt = 0; tt < 16; ++tt) {
            const int tok = sent[BSEL * SEQ + tb + tt];
            x_s[tt][j] = emb[(size_t)tok * EMB + j];
        }
    }
    __syncthreads();

    float4 wf4[25], wb4[25];
    const float4* wfp = (const float4*)(Wf_ih + (size_t)j * EMB);
    const float4* wbp = (const float4*)(Wb_ih + (size_t)j * EMB);
#pragma unroll
    for (int m = 0; m < 25; ++m) { wf4[m] = wfp[m]; wb4[m] = wbp[m]; }
    const float bf = bf_ih[j], bb = bb_ih[j];

    const int g  = j >> 7;
    const int u  = j & 127;
    const int u2 = u >> 1;
    const size_t orow = ((size_t)(g * 64 + u2)) * SEQ;

    for (int tt = 0; tt < 16; ++tt) {
        const float4* xs = (const float4*)(x_s[tt]);
        float af = 0.f, ab = 0.f;
#pragma unroll
        for (int m = 0; m < 25; ++m) {
            const float4 xv = xs[m];
            af = fmaf(wf4[m].x, xv.x, af); af = fmaf(wf4[m].y, xv.y, af);
            af = fmaf(wf4[m].z, xv.z, af); af = fmaf(wf4[m].w, xv.w, af);
            ab = fmaf(wb4[m].x, xv.x, ab); ab = fmaf(wb4[m].y, xv.y, ab);
            ab = fmaf(wb4[m].z, xv.z, ab); ab = fmaf(wb4[m].w, xv.w, ab);
        }
        const float vf = af + bf;
        const float vb = ab + bb;
        const float vf_n = __shfl_xor(vf, 1);
        const float vb_n = __shfl_xor(vb, 1);
        if ((u & 1) == 0) {
            gi_ft[orow + tb + tt] = pack_f16(vf, vf_n);
            gi_bt[orow + tb + tt] = pack_f16(vb, vb_n);
        }
    }
}

// ---------------------------------------------------------------------------
// Kernel 2: GRU recurrence, 256 threads/block (one block per direction),
// 1 wave/SIMD (512-VGPR budget; weights resident — R11: VGPR_Count 132).
// Thread = (unit u = tid>>1, half = tid&1 -> 64-col slice).
// Per step: 8 broadcast ds_read_b128 used DIRECTLY by 96 v_dot2 (no unpack
// array — R11's ~32 movs/step removed), one DPP pair-add, gates redundant
// on both lanes, half==0 writes h.
// gi loaded once per 16-STEP window (quad = unit-pair u2; lane kq holds
// slots 4s+kq); h outputs buffered, stored once per window -> per-step
// barrier drains nothing; one vmcnt drain per 16 steps.
// ---------------------------------------------------------------------------
template <int DIR>
__device__ void gru_run(const uint32_t* __restrict__ git,
                        const float* __restrict__ Whh,
                        const float* __restrict__ bhh,
                        const float* __restrict__ h0,
                        float* __restrict__ outs)
{
    const int tid  = threadIdx.x;         // 0..255
    const int u    = tid >> 1;            // unit 0..127
    const int half = tid & 1;             // 64-col slice
    const int u2   = u >> 1;              // quad index
    const int kq   = tid & 3;             // lane-in-quad
    const int halfu = u & 1;              // which half of the u2 pack

    // --- weights: rows {u, 128+u, 256+u}, cols [64*half, 64*half+64), f16
    uint32_t Wp0[32], Wp1[32], Wp2[32];
    {
        const float* r0 = Whh + (size_t)u * HID + 64 * half;
        const float* r1 = Whh + (size_t)(HID + u) * HID + 64 * half;
        const float* r2 = Whh + (size_t)(2 * HID + u) * HID + 64 * half;
#pragma unroll
        for (int m4 = 0; m4 < 16; ++m4) {
            const float4 a = ((const float4*)r0)[m4];
            const float4 b = ((const float4*)r1)[m4];
            const float4 c = ((const float4*)r2)[m4];
            Wp0[2 * m4] = pack_f16(a.x, a.y); Wp0[2 * m4 + 1] = pack_f16(a.z, a.w);
            Wp1[2 * m4] = pack_f16(b.x, b.y); Wp1[2 * m4 + 1] = pack_f16(b.z, b.w);
            Wp2[2 * m4] = pack_f16(c.x, c.y); Wp2[2 * m4 + 1] = pack_f16(c.z, c.w);
        }
#pragma unroll
        for (int m = 0; m < 32; ++m) { KEEPI(Wp0[m]); KEEPI(Wp1[m]); KEEPI(Wp2[m]); }
    }

    const float b_r = bhh[u];
    const float b_z = bhh[HID + u];
    const float b_n = bhh[2 * HID + u];

    float h_u = h0[(size_t)DIR * BATCH * HID + BSEL * HID + u];

    const uint32_t* grb = git + (size_t)(0 * 64 + u2) * SEQ;
    const uint32_t* gzb = git + (size_t)(1 * 64 + u2) * SEQ;
    const uint32_t* gnb = git + (size_t)(2 * 64 + u2) * SEQ;

    __shared__ __align__(16) uint32_t h_lds[2][HID / 2];
    if (tid < HID / 2) {
        const float2 hh = *(const float2*)(h0 + (size_t)DIR * BATCH * HID + BSEL * HID + 2 * tid);
        h_lds[0][tid] = pack_f16(hh.x, hh.y);
    }

    // window-0 gi: lane kq holds in-window t-slots 4s+kq, s=0..3
    uint32_t gcu[4][3];
    {
        const int bt = DIR ? (SEQ - 16) : 0;
#pragma unroll
        for (int s = 0; s < 4; ++s) {
            gcu[s][0] = grb[bt + 4 * s + kq];
            gcu[s][1] = gzb[bt + 4 * s + kq];
            gcu[s][2] = gnb[bt + 4 * s + kq];
        }
    }
    __syncthreads();   // drains prologue loads once

    float hs0 = 0, hs1 = 0, hs2 = 0, hs3 = 0, hs4 = 0, hs5 = 0, hs6 = 0, hs7 = 0,
          hs8 = 0, hs9 = 0, hs10 = 0, hs11 = 0, hs12 = 0, hs13 = 0, hs14 = 0, hs15 = 0;

// 12 dot2 on one uint4's components (weights index constant -> registers)
#define DOTQ(m, q) \
    ar = dot2(Wp0[4*(m)+0], (q).x, ar); az = dot2(Wp1[4*(m)+0], (q).x, az); an = dot2(Wp2[4*(m)+0], (q).x, an); \
    ar = dot2(Wp0[4*(m)+1], (q).y, ar); az = dot2(Wp1[4*(m)+1], (q).y, az); an = dot2(Wp2[4*(m)+1], (q).y, an); \
    ar = dot2(Wp0[4*(m)+2], (q).z, ar); az = dot2(Wp1[4*(m)+2], (q).z, az); an = dot2(Wp2[4*(m)+2], (q).z, an); \
    ar = dot2(Wp0[4*(m)+3], (q).w, ar); az = dot2(Wp1[4*(m)+3], (q).w, az); an = dot2(Wp2[4*(m)+3], (q).w, an);

#define GRU_STEP(I, KIDX) do {                                                 \
    const uint4* hb4 = (const uint4*)(h_lds[(I) & 1]) + half * 8;              \
    const uint4 q0 = hb4[0], q1 = hb4[1], q2 = hb4[2], q3 = hb4[3];            \
    const uint4 q4 = hb4[4], q5 = hb4[5], q6 = hb4[6], q7 = hb4[7];            \
    float ar = 0.f, az = 0.f, an = 0.f;                                        \
    DOTQ(0, q0) DOTQ(1, q1) DOTQ(2, q2) DOTQ(3, q3)                            \
    DOTQ(4, q4) DOTQ(5, q5) DOTQ(6, q6) DOTQ(7, q7)                            \
    ar = dpp_add<0xB1>(ar);                                                    \
    az = dpp_add<0xB1>(az);                                                    \
    an = dpp_add<0xB1>(an);                                                    \
    const uint32_t gur = dpp_bcast<((KIDX) & 3) * 0x55>(gcu[(KIDX) >> 2][0]);  \
    const uint32_t guz = dpp_bcast<((KIDX) & 3) * 0x55>(gcu[(KIDX) >> 2][1]);  \
    const uint32_t gun = dpp_bcast<((KIDX) & 3) * 0x55>(gcu[(KIDX) >> 2][2]);  \
    const float gr = half_sel(gur, halfu) + b_r;                               \
    const float gz = half_sel(guz, halfu) + b_z;                               \
    const float gn = half_sel(gun, halfu);                                     \
    const float rg = __builtin_amdgcn_rcpf(1.f + __expf(-(gr + ar)));          \
    const float zg = __builtin_amdgcn_rcpf(1.f + __expf(-(gz + az)));          \
    float ttv = gn + rg * (an + b_n);                                          \
    ttv = fminf(fmaxf(ttv, -15.f), 15.f);                                      \
    const float e = __expf(-2.f * ttv);                                        \
    const float ng = fmaf(2.f, __builtin_amdgcn_rcpf(1.f + e), -1.f);          \
    h_u = (1.f - zg) * ng + zg * h_u;                                          \
    if (half == 0) {                                                           \
        hs##I = h_u;                                                           \
        ((_Float16*)(h_lds[((I) & 1) ^ 1]))[u] = (_Float16)h_u;                \
    }                                                                          \
    __syncthreads();                                                           \
} while (0)

    constexpr int NW = SEQ / 16;
    for (int w = 0; w < NW; ++w) {
        GRU_STEP(0,  (DIR ? 15 : 0));
        GRU_STEP(1,  (DIR ? 14 : 1));
        GRU_STEP(2,  (DIR ? 13 : 2));
        GRU_STEP(3,  (DIR ? 12 : 3));
        GRU_STEP(4,  (DIR ? 11 : 4));
        GRU_STEP(5,  (DIR ? 10 : 5));
        GRU_STEP(6,  (DIR ? 9  : 6));
        GRU_STEP(7,  (DIR ? 8  : 7));
        GRU_STEP(8,  (DIR ? 7  : 8));
        GRU_STEP(9,  (DIR ? 6  : 9));
        GRU_STEP(10, (DIR ? 5  : 10));
        GRU_STEP(11, (DIR ? 4  : 11));
        GRU_STEP(12, (DIR ? 3  : 12));
        GRU_STEP(13, (DIR ? 2  : 13));
        GRU_STEP(14, (DIR ? 1  : 14));
        GRU_STEP(15, (DIR ? 0  : 15));

        // window-end writeback (half==0 lanes: this unit's 16 timesteps)
        if (half == 0) {
            const int t0 = DIR ? (SEQ - 1 - 16 * w) : 16 * w;
            const int ti = DIR ? -1 : 1;
            outs[(size_t)(t0 + 0  * ti) * HID + u] = hs0;
            outs[(size_t)(t0 + 1  * ti) * HID + u] = hs1;
            outs[(size_t)(t0 + 2  * ti) * HID + u] = hs2;
            outs[(size_t)(t0 + 3  * ti) * HID + u] = hs3;
            outs[(size_t)(t0 + 4  * ti) * HID + u] = hs4;
            outs[(size_t)(t0 + 5  * ti) * HID + u] = hs5;
            outs[(size_t)(t0 + 6  * ti) * HID + u] = hs6;
            outs[(size_t)(t0 + 7  * ti) * HID + u] = hs7;
            outs[(size_t)(t0 + 8  * ti) * HID + u] = hs8;
            outs[(size_t)(t0 + 9  * ti) * HID + u] = hs9;
            outs[(size_t)(t0 + 10 * ti) * HID + u] = hs10;
            outs[(size_t)(t0 + 11 * ti) * HID + u] = hs11;
            outs[(size_t)(t0 + 12 * ti) * HID + u] = hs12;
            outs[(size_t)(t0 + 13 * ti) * HID + u] = hs13;
            outs[(size_t)(t0 + 14 * ti) * HID + u] = hs14;
            outs[(size_t)(t0 + 15 * ti) * HID + u] = hs15;
        }
        // next-window gi (drained at next window's first barrier)
        if (w + 1 < NW) {
            const int bt = DIR ? (SEQ - 16 - 16 * (w + 1)) : (16 * (w + 1));
#pragma unroll
            for (int s = 0; s < 4; ++s) {
                gcu[s][0] = grb[bt + 4 * s + kq];
                gcu[s][1] = gzb[bt + 4 * s + kq];
                gcu[s][2] = gnb[bt + 4 * s + kq];
            }
        }
    }
#undef GRU_STEP
#undef DOTQ
}

__global__ __launch_bounds__(256)
__attribute__((amdgpu_waves_per_eu(1, 1)))
void k_recur(
    const uint32_t* __restrict__ gi_ft, const uint32_t* __restrict__ gi_bt,
    const float* __restrict__ Wf_hh, const float* __restrict__ bf_hh,
    const float* __restrict__ Wb_hh, const float* __restrict__ bb_hh,
    const float* __restrict__ h0,
    float* __restrict__ fwd, float* __restrict__ bwd)
{
    if (blockIdx.x == 0) gru_run<0>(gi_ft, Wf_hh, bf_hh, h0, fwd);
    else                 gru_run<1>(gi_bt, Wb_hh, bb_hh, h0, bwd);
}

// ---------------------------------------------------------------------------
// Kernel 3a: logits + softmax, PARALLEL over t (8 blocks x 256 t each).
// (R10-verified, unchanged)
// ---------------------------------------------------------------------------
__global__ __launch_bounds__(256) void k_logits(
    const float* __restrict__ fwd, const float* __restrict__ bwd,
    const float* __restrict__ W_out, const float* __restrict__ b_out,
    float* __restrict__ probs)
{
    __shared__ __align__(16) float4 Wl[NS][64];   // 6KB = 384 float4
    __shared__ float bl[NS];

    const int tid = threadIdx.x;
    for (int i = tid; i < NS * 64; i += 256)
        Wl[i >> 6][i & 63] = ((const float4*)W_out)[i];
    if (tid < NS) bl[tid] = b_out[tid];
    __syncthreads();

    const int t = blockIdx.x * 256 + tid;
    const float4* f4 = (const float4*)(fwd + (size_t)t * HID);
    const float4* b4 = (const float4*)(bwd + (size_t)t * HID);
    float lg[NS];
#pragma unroll
    for (int s = 0; s < NS; ++s) lg[s] = bl[s];
#pragma unroll 4
    for (int k4 = 0; k4 < 32; ++k4) {
        const float4 fv = f4[k4];
        const float4 bv = b4[k4];
#pragma unroll
        for (int s = 0; s < NS; ++s) {
            const float4 wf = Wl[s][k4];
            const float4 wb = Wl[s][k4 + 32];
            lg[s] += wf.x * fv.x + wf.y * fv.y + wf.z * fv.z + wf.w * fv.w
                   + wb.x * bv.x + wb.y * bv.y + wb.z * bv.z + wb.w * bv.w;
        }
    }
    float m = lg[0];
#pragma unroll
    for (int s = 1; s < NS; ++s) m = fmaxf(m, lg[s]);
    float sum = 0.f;
#pragma unroll
    for (int s = 0; s < NS; ++s) { lg[s] = __expf(lg[s] - m); sum += lg[s]; }
    const float inv = 1.f / sum;
    float* po = probs + (size_t)t * NS;
    *(float2*)(po)     = float2{lg[0] * inv, lg[1] * inv};
    *(float2*)(po + 2) = float2{lg[2] * inv, lg[3] * inv};
    *(float2*)(po + 4) = float2{lg[4] * inv, lg[5] * inv};
}

// ---------------------------------------------------------------------------
// Kernel 3b: PARALLEL Viterbi via (max,+) segmented scan + backtrack.
// (R10-verified, unchanged)
// ---------------------------------------------------------------------------
__global__ __launch_bounds__(G3) void k_viterbi(
    const float* __restrict__ probs, const float* __restrict__ trans,
    float* __restrict__ out)
{
    __shared__ float p_lds[SEQ * NS];
    __shared__ uint32_t bp32[SEQ - 1];
    __shared__ float Pmat[32][NS][NS];
    __shared__ float vstart[32][NS];
    __shared__ unsigned char cmap[32 * NS];
    __shared__ int bstate[32];
    __shared__ int s_last;

    const int tid = threadIdx.x;

    {
        const float4* src = (const float4*)probs;
        float4* dst = (float4*)p_lds;
#pragma unroll
        for (int r = 0; r < 8; ++r) dst[tid + r * G3] = src[tid + r * G3];
    }
    __syncthreads();

    if (tid < 32 * NS) {
        const int c = tid / NS, i = tid % NS;
        float tc[NS][NS];
#pragma unroll
        for (int k = 0; k < NS; ++k)
#pragma unroll
            for (int j = 0; j < NS; ++j) tc[k][j] = trans[k * NS + j];
        float R[NS];
#pragma unroll
        for (int j = 0; j < NS; ++j) R[j] = (j == i) ? 0.f : -3.0e38f;
        const int lo = 64 * c;
        const int hi = (c == 31) ? (SEQ - 1) : 64 * (c + 1);
        for (int tau = lo + 1; tau <= hi; ++tau) {
            const float2 p01 = *(const float2*)&p_lds[tau * NS];
            const float2 p23 = *(const float2*)&p_lds[tau * NS + 2];
            const float2 p45 = *(const float2*)&p_lds[tau * NS + 4];
            const float pj[NS] = {p01.x, p01.y, p23.x, p23.y, p45.x, p45.y};
            float Rn[NS];
#pragma unroll
            for (int j = 0; j < NS; ++j) {
                float mx = R[0] + tc[0][j];
                mx = fmaxf(mx, R[1] + tc[1][j]);
                mx = fmaxf(mx, R[2] + tc[2][j]);
                mx = fmaxf(mx, R[3] + tc[3][j]);
                mx = fmaxf(mx, R[4] + tc[4][j]);
                mx = fmaxf(mx, R[5] + tc[5][j]);
                Rn[j] = mx + pj[j];
            }
#pragma unroll
            for (int j = 0; j < NS; ++j) R[j] = Rn[j];
        }
#pragma unroll
        for (int j = 0; j < NS; ++j) Pmat[c][i][j] = R[j];
    }
    __syncthreads();

    if (tid == 0) {
        float v[NS];
#pragma unroll
        for (int j = 0; j < NS; ++j) { v[j] = p_lds[j]; vstart[0][j] = v[j]; }
        for (int c = 0; c < 31; ++c) {
            float vn[NS];
#pragma unroll
            for (int j = 0; j < NS; ++j) {
                float mx = v[0] + Pmat[c][0][j];
                mx = fmaxf(mx, v[1] + Pmat[c][1][j]);
                mx = fmaxf(mx, v[2] + Pmat[c][2][j]);
                mx = fmaxf(mx, v[3] + Pmat[c][3][j]);
                mx = fmaxf(mx, v[4] + Pmat[c][4][j]);
                mx = fmaxf(mx, v[5] + Pmat[c][5][j]);
                vn[j] = mx;
            }
#pragma unroll
            for (int j = 0; j < NS; ++j) { v[j] = vn[j]; vstart[c + 1][j] = vn[j]; }
        }
    }
    __syncthreads();

    if (tid < 32) {
        const int c = tid;
        float tc[NS][NS];
#pragma unroll
        for (int k = 0; k < NS; ++k)
#pragma unroll
            for (int j = 0; j < NS; ++j) tc[k][j] = trans[k * NS + j];
        float v[NS];
#pragma unroll
        for (int j = 0; j < NS; ++j) v[j] = vstart[c][j];
        const int lo = 64 * c;
        const int hi = (c == 31) ? (SEQ - 1) : 64 * (c + 1);
        for (int tau = lo + 1; tau <= hi; ++tau) {
            const float2 p01 = *(const float2*)&p_lds[tau * NS];
            const float2 p23 = *(const float2*)&p_lds[tau * NS + 2];
            const float2 p45 = *(const float2*)&p_lds[tau * NS + 4];
            const float pj[NS] = {p01.x, p01.y, p23.x, p23.y, p45.x, p45.y};
            uint32_t bpw = 0;
            float vn[NS];
#pragma unroll
            for (int j = 0; j < NS; ++j) {
                const float c0 = v[0] + tc[0][j];
                const float c1 = v[1] + tc[1][j];
                const float c2 = v[2] + tc[2][j];
                const float c3 = v[3] + tc[3][j];
                const float c4 = v[4] + tc[4][j];
                const float c5 = v[5] + tc[5][j];
                const float best = fmaxf(fmaxf(fmaxf(c0, c1), c2),
                                         fmaxf(fmaxf(c3, c4), c5));
                int bi = 5;
                bi = (c4 == best) ? 4 : bi;
                bi = (c3 == best) ? 3 : bi;
                bi = (c2 == best) ? 2 : bi;
                bi = (c1 == best) ? 1 : bi;
                bi = (c0 == best) ? 0 : bi;
                bpw |= ((uint32_t)bi) << (3 * j);
                vn[j] = pj[j] + best;
            }
            bp32[tau - 1] = bpw;
#pragma unroll
            for (int j = 0; j < NS; ++j) v[j] = vn[j];
        }
        if (c == 31) {
            const float best = fmaxf(fmaxf(fmaxf(v[0], v[1]), v[2]),
                                     fmaxf(fmaxf(v[3], v[4]), v[5]));
            int bi = 5;
            bi = (v[4] == best) ? 4 : bi;
            bi = (v[3] == best) ? 3 : bi;
            bi = (v[2] == best) ? 2 : bi;
            bi = (v[1] == best) ? 1 : bi;
            bi = (v[0] == best) ? 0 : bi;
            out[0] = best; s_last = bi;
        }
    }
    __syncthreads();

    if (tid < 32 * NS) {
        const int c = tid / NS, s0 = tid % NS;
        const int hi = (c == 31) ? (SEQ - 1) : 64 * (c + 1);
        const int lo = 64 * c;
        int s = s0;
        for (int tau = hi; tau > lo; --tau)
            s = (bp32[tau - 1] >> (3 * s)) & 7;
        cmap[c * NS + s0] = (unsigned char)s;
    }
    __syncthreads();

    if (tid == 0) {
        int s = s_last;
        for (int c = 31; c >= 0; --c) {
            s = cmap[c * NS + s];
            bstate[c] = s;
        }
    }
    __syncthreads();

    if (tid < 32) {
        const int c = tid;
        const int hi = (c == 31) ? (SEQ - 1) : 64 * (c + 1);
        const int lo = 64 * c;
        int s = (c == 31) ? s_last : bstate[c + 1];
        for (int tau = hi; tau > lo; --tau) {
            out[1 + tau] = (float)s;
            s = (bp32[tau - 1] >> (3 * s)) & 7;
        }
        if (c == 0) out[1] = (float)s;   // time 0
    }
}

// ---------------------------------------------------------------------------
extern "C" void kernel_launch(void* const* d_in, const int* in_sizes, int n_in,
                              void* d_out, int out_size, void* d_ws, size_t ws_size,
                              hipStream_t stream)
{
    (void)in_sizes; (void)n_in; (void)out_size; (void)ws_size;

    const int*   sent  = (const int*)  d_in[0];
    const float* emb   = (const float*)d_in[1];
    const float* h0    = (const float*)d_in[2];
    const float* Wf_ih = (const float*)d_in[3];
    const float* Wf_hh = (const float*)d_in[4];
    const float* bf_ih = (const float*)d_in[5];
    const float* bf_hh = (const float*)d_in[6];
    const float* Wb_ih = (const float*)d_in[7];
    const float* Wb_hh = (const float*)d_in[8];
    const float* bb_ih = (const float*)d_in[9];
    const float* bb_hh = (const float*)d_in[10];
    const float* W_out = (const float*)d_in[11];
    const float* b_out = (const float*)d_in[12];
    const float* trans = (const float*)d_in[13];
    float* out = (float*)d_out;

    // workspace layout (floats): gi_ft | gi_bt | fwd | bwd.
    // probs aliases gi_ft (dead after k_recur).
    float*    ws    = (float*)d_ws;
    uint32_t* gi_ft = (uint32_t*)ws;
    uint32_t* gi_bt = gi_ft + (size_t)SEQ * 192;
    float*    fwdb  = ws + (size_t)2 * SEQ * G3;
    float*    bwdb  = fwdb + (size_t)SEQ * HID;
    float*    probs = ws;                     // alias of gi_ft region

    k_input_proj<<<SEQ / 16, G3, 0, stream>>>(sent, emb, Wf_ih, bf_ih, Wb_ih, bb_ih, gi_ft, gi_bt);
    k_recur<<<2, 256, 0, stream>>>(gi_ft, gi_bt, Wf_hh, bf_hh, Wb_hh, bb_hh, h0, fwdb, bwdb);
    k_logits<<<SEQ / 256, 256, 0, stream>>>(fwdb, bwdb, W_out, b_out, probs);
    k_viterbi<<<1, G3, 0, stream>>>(probs, trans, out);
}